// Round 1
// baseline (1102.131 us; speedup 1.0000x reference)
//
#include <hip/hip_runtime.h>
#include <cstdint>
#include <cstddef>

using u16 = unsigned short;
using bf16x8 = __attribute__((ext_vector_type(8))) short;
using f32x4  = __attribute__((ext_vector_type(4))) float;

__device__ __forceinline__ u16 f2bf(float f) {
  unsigned u = __float_as_uint(f);
  u += 0x7fffu + ((u >> 16) & 1u);
  return (u16)(u >> 16);
}
__device__ __forceinline__ float bf2f(u16 h) {
  return __uint_as_float(((unsigned)h) << 16);
}

__device__ __forceinline__ void gload_lds16(const void* g, void* l) {
  auto gp = reinterpret_cast<const __attribute__((address_space(1))) char*>(
      reinterpret_cast<uintptr_t>(g));
  auto lp = reinterpret_cast<__attribute__((address_space(3))) char*>(
      reinterpret_cast<uintptr_t>(l));
  __builtin_amdgcn_global_load_lds(gp, lp, 16, 0, 0);
}

// ---------- weight transpose + downcast: W f32[din][dout] -> WT bf16[dout][din]
__global__ __launch_bounds__(256) void transpose_to_bf16(
    const float* __restrict__ W, u16* __restrict__ WT, int din, int dout) {
  __shared__ float tile[32][33];
  const int j0 = blockIdx.x * 32;   // dout
  const int i0 = blockIdx.y * 32;   // din
  const int tx = threadIdx.x & 31;
  const int ty = threadIdx.x >> 5;  // 0..7
#pragma unroll
  for (int k = 0; k < 32; k += 8)
    tile[ty + k][tx] = W[(size_t)(i0 + ty + k) * dout + (j0 + tx)];
  __syncthreads();
#pragma unroll
  for (int k = 0; k < 32; k += 8)
    WT[(size_t)(j0 + ty + k) * din + (i0 + tx)] = f2bf(tile[tx][ty + k]);
}

// ---------- rmsnorm f32 -> bf16, one block per row of 1024
__global__ __launch_bounds__(256) void rmsnorm_kernel(
    const float* __restrict__ x, const float* __restrict__ g, u16* __restrict__ xn) {
  const int row = blockIdx.x;
  const float4 v = ((const float4*)(x + (size_t)row * 1024))[threadIdx.x];
  float ss = v.x * v.x + v.y * v.y + v.z * v.z + v.w * v.w;
#pragma unroll
  for (int off = 32; off > 0; off >>= 1) ss += __shfl_down(ss, off, 64);
  __shared__ float red[4];
  if ((threadIdx.x & 63) == 0) red[threadIdx.x >> 6] = ss;
  __syncthreads();
  const float rs = rsqrtf((red[0] + red[1] + red[2] + red[3]) * (1.f / 1024.f) + 1e-6f);
  const float4 gv = ((const float4*)g)[threadIdx.x];
  ushort4 o;
  o.x = f2bf(v.x * rs * gv.x);
  o.y = f2bf(v.y * rs * gv.y);
  o.z = f2bf(v.z * rs * gv.z);
  o.w = f2bf(v.w * rs * gv.w);
  ((ushort4*)(xn + (size_t)row * 1024))[threadIdx.x] = o;
}

// ---------- chunked linear-recurrence scan: h[l] = sig(-dt)*h[l-1] + sig(dt)*sig(lnz)
// pass1: per 64-step chunk compute (P = prod a, S = partial sum with h_in=0)
__global__ __launch_bounds__(256) void scan_pass1(
    const float* __restrict__ dt, const u16* __restrict__ lnz,
    float* __restrict__ P, float* __restrict__ S) {
  const int blk = blockIdx.x;              // B*64*4 = 1024 blocks
  const int dblk = blk & 3;
  const int chunk = (blk >> 2) & 63;
  const int b = blk >> 8;
  const int d = dblk * 256 + threadIdx.x;
  const size_t base = ((size_t)b * 4096 + (size_t)chunk * 64) * 1024 + d;
  float p = 1.f, s = 0.f;
#pragma unroll 8
  for (int l = 0; l < 64; ++l) {
    const float dtv = dt[base + (size_t)l * 1024];
    const float zv = bf2f(lnz[base + (size_t)l * 1024]);
    const float a = 1.f / (1.f + __expf(dtv));        // sigmoid(-dt)
    const float zs = 1.f / (1.f + __expf(-zv));       // sigmoid(lnz_pre)
    const float in = (1.f - a) * zs;                  // sigmoid(dt)*z
    p *= a;
    s = a * s + in;
  }
  const size_t o = ((size_t)b * 64 + chunk) * 1024 + d;
  P[o] = p;
  S[o] = s;
}

// pass2: combine chunk summaries sequentially (64 steps per channel)
__global__ __launch_bounds__(256) void scan_pass2(
    const float* __restrict__ P, const float* __restrict__ S,
    const float* __restrict__ hidden, float* __restrict__ hin) {
  const int idx = blockIdx.x * 256 + threadIdx.x;  // 0..4095
  const int b = idx >> 10, d = idx & 1023;
  float h = hidden[idx];
#pragma unroll 8
  for (int c = 0; c < 64; ++c) {
    const size_t o = ((size_t)b * 64 + c) * 1024 + d;
    hin[o] = h;
    h = P[o] * h + S[o];
  }
}

// pass3: recompute within chunk from the correct h_in, emit h (f32 + bf16)
__global__ __launch_bounds__(256) void scan_pass3(
    const float* __restrict__ dt, const u16* __restrict__ lnz,
    const float* __restrict__ hin, float* __restrict__ h_out, u16* __restrict__ hbf) {
  const int blk = blockIdx.x;
  const int dblk = blk & 3;
  const int chunk = (blk >> 2) & 63;
  const int b = blk >> 8;
  const int d = dblk * 256 + threadIdx.x;
  const size_t base = ((size_t)b * 4096 + (size_t)chunk * 64) * 1024 + d;
  float h = hin[((size_t)b * 64 + chunk) * 1024 + d];
#pragma unroll 4
  for (int l = 0; l < 64; ++l) {
    const float dtv = dt[base + (size_t)l * 1024];
    const float zv = bf2f(lnz[base + (size_t)l * 1024]);
    const float a = 1.f / (1.f + __expf(dtv));
    const float zs = 1.f / (1.f + __expf(-zv));
    h = a * h + (1.f - a) * zs;
    h_out[base + (size_t)l * 1024] = h;
    hbf[base + (size_t)l * 1024] = f2bf(h);
  }
}

// ---------- GEMM: C[M][N] = A[M][K] @ B^T  with B stored [N][K] (both bf16)
// 128x128 tile, BK=64, 4 waves (2x2), mfma 16x16x32, global_load_lds staging,
// XOR swizzle ((row&7)<<4) -> conflict-free ds_read_b128.
// EPI: 0 = f32 out (+bias)            (dt)
//      1 = bf16 out (+bias)           (lnz, yg)
//      2 = f32 out = (acc+b)*silu(gate) + resid      (y + residual)
//      3 = dual-B: bf16 out = (accA+b1)*silu(accB+b2)  (ff*silu(ffg))
//      4 = f32 out = acc + b + outF (in-place residual)  (ffo)
template <int EPI>
__global__ __launch_bounds__(256) void gemm_bt(
    const u16* __restrict__ A, const u16* __restrict__ B1, const u16* __restrict__ B2,
    const float* __restrict__ bias1, const float* __restrict__ bias2,
    const float* __restrict__ resid, const u16* __restrict__ gate,
    float* __restrict__ outF, u16* __restrict__ outH,
    int M, int N, int K) {
  constexpr bool DUAL = (EPI == 3);
  const int tid = threadIdx.x;
  const int lane = tid & 63;
  const int wv = tid >> 6;
  const int wr = wv >> 1;
  const int wc = wv & 1;
  const int m0 = blockIdx.y * 128;
  const int n0 = blockIdx.x * 128;

  __shared__ __align__(16) char sA[16384];
  __shared__ __align__(16) char sB[16384];
  __shared__ __align__(16) char sB2[DUAL ? 16384 : 16];

  f32x4 acc[4][4];
  f32x4 acc2[DUAL ? 4 : 1][DUAL ? 4 : 1];
#pragma unroll
  for (int m = 0; m < 4; ++m)
#pragma unroll
    for (int n = 0; n < 4; ++n) acc[m][n] = (f32x4){0.f, 0.f, 0.f, 0.f};
  if constexpr (DUAL) {
#pragma unroll
    for (int m = 0; m < 4; ++m)
#pragma unroll
      for (int n = 0; n < 4; ++n) acc2[m][n] = (f32x4){0.f, 0.f, 0.f, 0.f};
  }

  auto stage = [&](const u16* src, char* lds, int row0, int ldk, int k0) {
#pragma unroll
    for (int i = 0; i < 4; ++i) {
      const int f = (tid + i * 256) * 16;                 // byte offset in 16 KiB tile
      const int row = f >> 7;                             // 128 B per row (64 bf16)
      const int kb = (f & 127) ^ ((row & 7) << 4);        // inverse-swizzled source
      gload_lds16((const char*)(src + (size_t)(row0 + row) * ldk + k0) + kb, lds + f);
    }
  };

  const int KT = K >> 6;
  for (int kt = 0; kt < KT; ++kt) {
    stage(A, sA, m0, K, kt * 64);
    stage(B1, sB, n0, K, kt * 64);
    if constexpr (DUAL) stage(B2, sB2, n0, K, kt * 64);
    __syncthreads();  // drains vmcnt -> LDS valid

#pragma unroll
    for (int kh = 0; kh < 2; ++kh) {
      bf16x8 af[4], bfr[4];
      bf16x8 bf2v[DUAL ? 4 : 1];
      const int qb = kh * 64 + ((lane >> 4) << 4);
#pragma unroll
      for (int m = 0; m < 4; ++m) {
        const int row = wr * 64 + m * 16 + (lane & 15);
        af[m] = *(const bf16x8*)(sA + row * 128 + (qb ^ ((row & 7) << 4)));
      }
#pragma unroll
      for (int n = 0; n < 4; ++n) {
        const int row = wc * 64 + n * 16 + (lane & 15);
        const int off = row * 128 + (qb ^ ((row & 7) << 4));
        bfr[n] = *(const bf16x8*)(sB + off);
        if constexpr (DUAL) bf2v[n] = *(const bf16x8*)(sB2 + off);
      }
#pragma unroll
      for (int m = 0; m < 4; ++m)
#pragma unroll
        for (int n = 0; n < 4; ++n) {
          acc[m][n] = __builtin_amdgcn_mfma_f32_16x16x32_bf16(af[m], bfr[n], acc[m][n], 0, 0, 0);
          if constexpr (DUAL)
            acc2[m][n] = __builtin_amdgcn_mfma_f32_16x16x32_bf16(af[m], bf2v[n], acc2[m][n], 0, 0, 0);
        }
    }
    __syncthreads();
  }

  // epilogue: C/D layout col = lane&15, row = (lane>>4)*4 + reg (guide m89/m91)
#pragma unroll
  for (int m = 0; m < 4; ++m) {
#pragma unroll
    for (int n = 0; n < 4; ++n) {
      const int col = n0 + wc * 64 + n * 16 + (lane & 15);
#pragma unroll
      for (int j = 0; j < 4; ++j) {
        const int row = m0 + wr * 64 + m * 16 + ((lane >> 4) << 2) + j;
        const size_t o = (size_t)row * N + col;
        const float v = acc[m][n][j] + bias1[col];
        if constexpr (EPI == 0) {
          outF[o] = v;
        } else if constexpr (EPI == 1) {
          outH[o] = f2bf(v);
        } else if constexpr (EPI == 2) {
          const float gt = bf2f(gate[o]);
          const float sg = gt / (1.f + __expf(-gt));   // silu
          outF[o] = v * sg + resid[o];
        } else if constexpr (EPI == 3) {
          const float v2 = acc2[m][n][j] + bias2[col];
          const float sg = v2 / (1.f + __expf(-v2));
          outH[o] = f2bf(v * sg);
        } else if constexpr (EPI == 4) {
          outF[o] = v + outF[o];                        // in-place residual add
        }
      }
    }
  }
}

extern "C" void kernel_launch(void* const* d_in, const int* in_sizes, int n_in,
                              void* d_out, int out_size, void* d_ws, size_t ws_size,
                              hipStream_t stream) {
  const float* x      = (const float*)d_in[0];
  const float* hidden = (const float*)d_in[1];
  const float* w_ln_z = (const float*)d_in[2];
  const float* b_ln_z = (const float*)d_in[3];
  const float* w_dt   = (const float*)d_in[4];
  const float* b_dt   = (const float*)d_in[5];
  const float* w_y    = (const float*)d_in[6];
  const float* b_y    = (const float*)d_in[7];
  const float* w_yg   = (const float*)d_in[8];
  const float* b_yg   = (const float*)d_in[9];
  const float* w_ff   = (const float*)d_in[10];
  const float* b_ff   = (const float*)d_in[11];
  const float* w_ffg  = (const float*)d_in[12];
  const float* b_ffg  = (const float*)d_in[13];
  const float* w_ffo  = (const float*)d_in[14];
  const float* b_ffo  = (const float*)d_in[15];
  const float* g_sio  = (const float*)d_in[16];
  const float* g_ffn  = (const float*)d_in[17];

  char* ws = (char*)d_ws;
  const size_t MB = 1ull << 20;
  u16*   WT_dt  = (u16*)(ws + 0 * MB);     //  2 MiB  [1024][1024]
  u16*   WT_lnz = (u16*)(ws + 2 * MB);     //  2 MiB
  u16*   WT_y   = (u16*)(ws + 4 * MB);     //  2 MiB
  u16*   WT_yg  = (u16*)(ws + 6 * MB);     //  2 MiB
  u16*   WT_ff  = (u16*)(ws + 8 * MB);     //  8 MiB  [4096][1024]
  u16*   WT_ffg = (u16*)(ws + 16 * MB);    //  8 MiB
  u16*   WT_ffo = (u16*)(ws + 24 * MB);    //  8 MiB  [1024][4096]
  u16*   xn     = (u16*)(ws + 32 * MB);    // 32 MiB  [16384][1024] bf16 (reused as xn2)
  float* dtb    = (float*)(ws + 64 * MB);  // 64 MiB  [16384][1024] f32
  u16*   lnzb   = (u16*)(ws + 128 * MB);   // 32 MiB  bf16
  u16*   ygb    = (u16*)(ws + 160 * MB);   // 32 MiB  bf16
  u16*   ub     = (u16*)(ws + 64 * MB);    // 128 MiB overlay (dt/lnz/yg dead by then)
  u16*   hbf    = (u16*)(ws + 192 * MB);   // 32 MiB  bf16
  float* Pc     = (float*)(ws + 224 * MB); //  1 MiB  chunk products
  float* Sc     = (float*)(ws + 225 * MB); //  1 MiB  chunk partials
  float* hin    = (float*)(ws + 226 * MB); //  1 MiB  chunk entry states
  // total ws usage: 227 MiB

  float* x_out = (float*)d_out;
  float* h_out = (float*)d_out + (size_t)4 * 4096 * 1024;

  const int M = 16384, D = 1024, F = 4096;
  const dim3 tb(256);

  // 1) weight transposes -> bf16 [N][K]
  transpose_to_bf16<<<dim3(D / 32, D / 32), tb, 0, stream>>>(w_dt, WT_dt, D, D);
  transpose_to_bf16<<<dim3(D / 32, D / 32), tb, 0, stream>>>(w_ln_z, WT_lnz, D, D);
  transpose_to_bf16<<<dim3(D / 32, D / 32), tb, 0, stream>>>(w_y, WT_y, D, D);
  transpose_to_bf16<<<dim3(D / 32, D / 32), tb, 0, stream>>>(w_yg, WT_yg, D, D);
  transpose_to_bf16<<<dim3(F / 32, D / 32), tb, 0, stream>>>(w_ff, WT_ff, D, F);
  transpose_to_bf16<<<dim3(F / 32, D / 32), tb, 0, stream>>>(w_ffg, WT_ffg, D, F);
  transpose_to_bf16<<<dim3(D / 32, F / 32), tb, 0, stream>>>(w_ffo, WT_ffo, F, D);

  // 2) rmsnorm(x, g_sio) -> xn bf16
  rmsnorm_kernel<<<M, tb, 0, stream>>>(x, g_sio, xn);

  // 3) dt = xn@w_dt + b_dt (f32); lnz = xn@w_ln_z + b_ln_z (bf16); yg = xn@w_yg + b_yg (bf16)
  gemm_bt<0><<<dim3(D / 128, M / 128), tb, 0, stream>>>(xn, WT_dt, nullptr, b_dt, nullptr,
                                                        nullptr, nullptr, dtb, nullptr, M, D, D);
  gemm_bt<1><<<dim3(D / 128, M / 128), tb, 0, stream>>>(xn, WT_lnz, nullptr, b_ln_z, nullptr,
                                                        nullptr, nullptr, nullptr, lnzb, M, D, D);
  gemm_bt<1><<<dim3(D / 128, M / 128), tb, 0, stream>>>(xn, WT_yg, nullptr, b_yg, nullptr,
                                                        nullptr, nullptr, nullptr, ygb, M, D, D);

  // 4) chunked scan -> h (f32 to d_out) + h bf16
  scan_pass1<<<1024, tb, 0, stream>>>(dtb, lnzb, Pc, Sc);
  scan_pass2<<<16, tb, 0, stream>>>(Pc, Sc, hidden, hin);
  scan_pass3<<<1024, tb, 0, stream>>>(dtb, lnzb, hin, h_out, hbf);

  // 5) x1 = (h@w_y + b_y) * silu(yg) + x   -> d_out (x region)
  gemm_bt<2><<<dim3(D / 128, M / 128), tb, 0, stream>>>(hbf, WT_y, nullptr, b_y, nullptr,
                                                        x, ygb, x_out, nullptr, M, D, D);

  // 6) rmsnorm(x1, g_ffn) -> xn (reuse)
  rmsnorm_kernel<<<M, tb, 0, stream>>>(x_out, g_ffn, xn);

  // 7) u = (xn@w_ff + b_ff) * silu(xn@w_ffg + b_ffg)  bf16 [16384][4096]
  gemm_bt<3><<<dim3(F / 128, M / 128), tb, 0, stream>>>(xn, WT_ff, WT_ffg, b_ff, b_ffg,
                                                        nullptr, nullptr, nullptr, ub, M, F, D);

  // 8) x_out = u@w_ffo + b_ffo + x1   (in-place residual on d_out)
  gemm_bt<4><<<dim3(D / 128, M / 128), tb, 0, stream>>>(ub, WT_ffo, nullptr, b_ffo, nullptr,
                                                        nullptr, nullptr, x_out, nullptr, M, D, F);
}

// Round 3
// 789.627 us; speedup vs baseline: 1.3958x; 1.3958x over previous
//
#include <hip/hip_runtime.h>
#include <cstdint>
#include <cstddef>

using u16 = unsigned short;
using bf16x8 = __attribute__((ext_vector_type(8))) short;
using f32x4  = __attribute__((ext_vector_type(4))) float;

__device__ __forceinline__ u16 f2bf(float f) {
  unsigned u = __float_as_uint(f);
  u += 0x7fffu + ((u >> 16) & 1u);
  return (u16)(u >> 16);
}
__device__ __forceinline__ float bf2f(u16 h) {
  return __uint_as_float(((unsigned)h) << 16);
}

__device__ __forceinline__ void gload_lds16(const void* g, void* l) {
  auto gp = reinterpret_cast<const __attribute__((address_space(1))) char*>(
      reinterpret_cast<uintptr_t>(g));
  auto lp = reinterpret_cast<__attribute__((address_space(3))) char*>(
      reinterpret_cast<uintptr_t>(l));
  __builtin_amdgcn_global_load_lds(gp, lp, 16, 0, 0);
}

// ---------- weight transpose + downcast: W f32[din][dout] -> WT bf16[dout][din]
__global__ __launch_bounds__(256) void transpose_to_bf16(
    const float* __restrict__ W, u16* __restrict__ WT, int din, int dout) {
  __shared__ float tile[32][33];
  const int j0 = blockIdx.x * 32;   // dout
  const int i0 = blockIdx.y * 32;   // din
  const int tx = threadIdx.x & 31;
  const int ty = threadIdx.x >> 5;  // 0..7
#pragma unroll
  for (int k = 0; k < 32; k += 8)
    tile[ty + k][tx] = W[(size_t)(i0 + ty + k) * dout + (j0 + tx)];
  __syncthreads();
#pragma unroll
  for (int k = 0; k < 32; k += 8)
    WT[(size_t)(j0 + ty + k) * din + (i0 + tx)] = f2bf(tile[tx][ty + k]);
}

// ---------- rmsnorm f32 -> bf16, one block per row of 1024
__global__ __launch_bounds__(256) void rmsnorm_kernel(
    const float* __restrict__ x, const float* __restrict__ g, u16* __restrict__ xn) {
  const int row = blockIdx.x;
  const float4 v = ((const float4*)(x + (size_t)row * 1024))[threadIdx.x];
  float ss = v.x * v.x + v.y * v.y + v.z * v.z + v.w * v.w;
#pragma unroll
  for (int off = 32; off > 0; off >>= 1) ss += __shfl_down(ss, off, 64);
  __shared__ float red[4];
  if ((threadIdx.x & 63) == 0) red[threadIdx.x >> 6] = ss;
  __syncthreads();
  const float rs = rsqrtf((red[0] + red[1] + red[2] + red[3]) * (1.f / 1024.f) + 1e-6f);
  const float4 gv = ((const float4*)g)[threadIdx.x];
  ushort4 o;
  o.x = f2bf(v.x * rs * gv.x);
  o.y = f2bf(v.y * rs * gv.y);
  o.z = f2bf(v.z * rs * gv.z);
  o.w = f2bf(v.w * rs * gv.w);
  ((ushort4*)(xn + (size_t)row * 1024))[threadIdx.x] = o;
}

// ---------- chunked linear-recurrence scan: h[l] = sig(-dt)*h[l-1] + sig(dt)*sig(lnz)
__global__ __launch_bounds__(256) void scan_pass1(
    const u16* __restrict__ dt, const u16* __restrict__ lnz,
    float* __restrict__ P, float* __restrict__ S) {
  const int blk = blockIdx.x;              // B*64*4 = 1024 blocks
  const int dblk = blk & 3;
  const int chunk = (blk >> 2) & 63;
  const int b = blk >> 8;
  const int d = dblk * 256 + threadIdx.x;
  const size_t base = ((size_t)b * 4096 + (size_t)chunk * 64) * 1024 + d;
  float p = 1.f, s = 0.f;
#pragma unroll 8
  for (int l = 0; l < 64; ++l) {
    const float dtv = bf2f(dt[base + (size_t)l * 1024]);
    const float zv = bf2f(lnz[base + (size_t)l * 1024]);
    const float a = 1.f / (1.f + __expf(dtv));        // sigmoid(-dt)
    const float zs = 1.f / (1.f + __expf(-zv));       // sigmoid(lnz_pre)
    const float in = (1.f - a) * zs;
    p *= a;
    s = a * s + in;
  }
  const size_t o = ((size_t)b * 64 + chunk) * 1024 + d;
  P[o] = p;
  S[o] = s;
}

__global__ __launch_bounds__(256) void scan_pass2(
    const float* __restrict__ P, const float* __restrict__ S,
    const float* __restrict__ hidden, float* __restrict__ hin) {
  const int idx = blockIdx.x * 256 + threadIdx.x;  // 0..4095
  const int b = idx >> 10, d = idx & 1023;
  float h = hidden[idx];
#pragma unroll 8
  for (int c = 0; c < 64; ++c) {
    const size_t o = ((size_t)b * 64 + c) * 1024 + d;
    hin[o] = h;
    h = P[o] * h + S[o];
  }
}

__global__ __launch_bounds__(256) void scan_pass3(
    const u16* __restrict__ dt, const u16* __restrict__ lnz,
    const float* __restrict__ hin, float* __restrict__ h_out, u16* __restrict__ hbf) {
  const int blk = blockIdx.x;
  const int dblk = blk & 3;
  const int chunk = (blk >> 2) & 63;
  const int b = blk >> 8;
  const int d = dblk * 256 + threadIdx.x;
  const size_t base = ((size_t)b * 4096 + (size_t)chunk * 64) * 1024 + d;
  float h = hin[((size_t)b * 64 + chunk) * 1024 + d];
#pragma unroll 4
  for (int l = 0; l < 64; ++l) {
    const float dtv = bf2f(dt[base + (size_t)l * 1024]);
    const float zv = bf2f(lnz[base + (size_t)l * 1024]);
    const float a = 1.f / (1.f + __expf(dtv));
    const float zs = 1.f / (1.f + __expf(-zv));
    h = a * h + (1.f - a) * zs;
    h_out[base + (size_t)l * 1024] = h;
    hbf[base + (size_t)l * 1024] = f2bf(h);
  }
}

// ---------- 256x256 8-phase GEMM: C[M][N] = A[M][K] @ B^T, B stored [N][K] bf16.
// 8 waves (2Mx4N), per-wave 128x64 out, BK=64, ring of 9 half-tile LDS slots
// (144 KiB), counted vmcnt(4), raw s_barrier, setprio around MFMA.
// EPI: 5 = fused3: bf16 outs {outH=dt, outH2=lnz, outH3=yg}, row stride 1024
//      2 = f32 out = (acc+b)*silu(gate bf16) + resid
//      6 = bf16 out = silu(acc+b)
//      7 = bf16 out = (acc+b)*bf2f(gate)   (gate may alias outH: in-place)
//      4 = f32 out = acc + b + outF (in-place residual add)
template <int EPI>
__global__ __launch_bounds__(512) void gemm256(
    const u16* __restrict__ A, const u16* __restrict__ B,
    const float* __restrict__ bias, const u16* __restrict__ gate,
    const float* __restrict__ resid, float* __restrict__ outF,
    u16* __restrict__ outH, u16* __restrict__ outH2, u16* __restrict__ outH3,
    int ntx, int N, int K) {
  const int tid = threadIdx.x;
  const int lane = tid & 63;
  const int wid = tid >> 6;
  const int wr = wid >> 2;   // 0..1 -> A half
  const int wc = wid & 3;    // 0..3 -> 64-col strip; wc>>1 -> B half

  // XCD-aware swizzle (grid %8==0 for all our launches)
  const int nwg = gridDim.x;
  int id = blockIdx.x;
  id = (id & 7) * (nwg >> 3) + (id >> 3);
  const int m0 = (id / ntx) * 256;
  const int n0 = (id % ntx) * 256;

  __shared__ __align__(16) char lds[9 * 16384];

  f32x4 acc[8][4];
#pragma unroll
  for (int m = 0; m < 8; ++m)
#pragma unroll
    for (int n = 0; n < 4; ++n) acc[m][n] = (f32x4){0.f, 0.f, 0.f, 0.f};

  bf16x8 aR[4][2], bR[4][2];

  const int NT = K >> 6;
  const int HT = NT << 2;

  // half-tile h: tile t=h>>2, part h&3: 0=A rows[0..127], 1=A rows[128..255],
  // 2=B rows[0..127], 3=B rows[128..255]. slot = h%9 -> 16 KiB each.
  auto stage = [&](int h) {
    if (h >= HT) return;
    const int slot = h % 9;
    const int part = h & 3;
    const int kt = h >> 2;
    const u16* src = (part < 2) ? A : B;
    const int r0 = ((part < 2) ? m0 : n0) + (part & 1) * 128;
    char* base = lds + slot * 16384;
#pragma unroll
    for (int i = 0; i < 2; ++i) {
      const int f = (tid + i * 512) * 16;            // 16 KiB over 512 thr x2
      const int row = f >> 7;                        // 128 B per row
      const int kb = (f & 127) ^ ((row & 7) << 4);   // inverse swizzle on src
      gload_lds16((const char*)(src + (size_t)(r0 + row) * K + kt * 64) + kb, base + f);
    }
  };

#define READA(SLOT, QM)                                                        \
  {                                                                            \
    const char* _b = lds + (SLOT) * 16384;                                     \
    _Pragma("unroll") for (int m = 0; m < 4; ++m) {                            \
      const int hr = (QM) * 64 + m * 16 + (lane & 15);                         \
      _Pragma("unroll") for (int k = 0; k < 2; ++k) {                          \
        aR[m][k] = *(const bf16x8*)(_b + hr * 128 +                            \
                    ((k * 64 + ((lane >> 4) << 4)) ^ ((hr & 7) << 4)));        \
      }                                                                        \
    }                                                                          \
  }

#define READB(SLOT, NP)                                                        \
  {                                                                            \
    const char* _b = lds + (SLOT) * 16384;                                     \
    _Pragma("unroll") for (int n = 0; n < 2; ++n) {                            \
      const int hr = (wc & 1) * 64 + ((NP) + n) * 16 + (lane & 15);            \
      _Pragma("unroll") for (int k = 0; k < 2; ++k) {                          \
        bR[(NP) + n][k] = *(const bf16x8*)(_b + hr * 128 +                     \
                    ((k * 64 + ((lane >> 4) << 4)) ^ ((hr & 7) << 4)));        \
      }                                                                        \
    }                                                                          \
  }

#define MMAQ(QM, QN)                                                           \
  __builtin_amdgcn_s_setprio(1);                                               \
  _Pragma("unroll") for (int m = 0; m < 4; ++m)                                \
  _Pragma("unroll") for (int n = 0; n < 2; ++n)                                \
  _Pragma("unroll") for (int k = 0; k < 2; ++k)                                \
      acc[(QM) * 4 + m][(QN) * 2 + n] = __builtin_amdgcn_mfma_f32_16x16x32_bf16( \
          aR[m][k], bR[(QN) * 2 + n][k], acc[(QM) * 4 + m][(QN) * 2 + n], 0, 0, 0); \
  __builtin_amdgcn_s_setprio(0);

  // prologue: stage halves 0..5 (tile0 complete + tile1 A0,A1)
#pragma unroll
  for (int h = 0; h < 6; ++h) stage(h);
  asm volatile("s_waitcnt vmcnt(4)" ::: "memory");
  __builtin_amdgcn_s_barrier();

  for (int t = 0; t < NT; ++t) {
    const int sA = (4 * t + wr) % 9;
    const int sB = (4 * t + 2 + (wc >> 1)) % 9;
    const int hb = 4 * t + 6;
    // phase 0: A(qm0) 8 reads + B(n0,1) 4 reads; stage t+1 B0
    READA(sA, 0);
    READB(sB, 0);
    stage(hb);
    __builtin_amdgcn_s_barrier();
    MMAQ(0, 0);
    __builtin_amdgcn_s_barrier();
    // phase 1: B(n2,3) 4 reads; stage t+1 B1
    READB(sB, 2);
    stage(hb + 1);
    __builtin_amdgcn_s_barrier();
    MMAQ(0, 1);
    __builtin_amdgcn_s_barrier();
    // phase 2: A(qm1) 8 reads; stage t+2 A0
    READA(sA, 1);
    stage(hb + 2);
    __builtin_amdgcn_s_barrier();
    MMAQ(1, 0);
    __builtin_amdgcn_s_barrier();
    // phase 3: stage t+2 A1; counted vmcnt -> next tile fully staged
    stage(hb + 3);
    __builtin_amdgcn_s_barrier();
    MMAQ(1, 1);
    if (t < NT - 2) asm volatile("s_waitcnt vmcnt(4)" ::: "memory");
    else            asm volatile("s_waitcnt vmcnt(0)" ::: "memory");
    __builtin_amdgcn_s_barrier();
  }

  // epilogue: C/D layout col = lane&15, row = (lane>>4)*4 + j
#pragma unroll
  for (int m = 0; m < 8; ++m) {
#pragma unroll
    for (int n = 0; n < 4; ++n) {
      const int col = n0 + wc * 64 + n * 16 + (lane & 15);
#pragma unroll
      for (int j = 0; j < 4; ++j) {
        const int row = m0 + wr * 128 + m * 16 + ((lane >> 4) << 2) + j;
        const float v = acc[m][n][j] + bias[col];
        if constexpr (EPI == 5) {
          const int rg = col >> 10;                     // block-uniform
          const size_t o = (size_t)row * 1024 + (col & 1023);
          if (rg == 0) outH[o] = f2bf(v);
          else if (rg == 1) outH2[o] = f2bf(v);
          else outH3[o] = f2bf(v);
        } else {
          const size_t o = (size_t)row * N + col;
          if constexpr (EPI == 2) {
            const float gt = bf2f(gate[o]);
            outF[o] = v * (gt / (1.f + __expf(-gt))) + resid[o];
          } else if constexpr (EPI == 6) {
            outH[o] = f2bf(v / (1.f + __expf(-v)));
          } else if constexpr (EPI == 7) {
            outH[o] = f2bf(v * bf2f(gate[o]));          // gate==outH ok (RAW per elem)
          } else if constexpr (EPI == 4) {
            outF[o] = v + outF[o];
          }
        }
      }
    }
  }
#undef READA
#undef READB
#undef MMAQ
}

extern "C" void kernel_launch(void* const* d_in, const int* in_sizes, int n_in,
                              void* d_out, int out_size, void* d_ws, size_t ws_size,
                              hipStream_t stream) {
  const float* x      = (const float*)d_in[0];
  const float* hidden = (const float*)d_in[1];
  const float* w_ln_z = (const float*)d_in[2];
  const float* b_ln_z = (const float*)d_in[3];
  const float* w_dt   = (const float*)d_in[4];
  const float* b_dt   = (const float*)d_in[5];
  const float* w_y    = (const float*)d_in[6];
  const float* b_y    = (const float*)d_in[7];
  const float* w_yg   = (const float*)d_in[8];
  const float* b_yg   = (const float*)d_in[9];
  const float* w_ff   = (const float*)d_in[10];
  const float* b_ff   = (const float*)d_in[11];
  const float* w_ffg  = (const float*)d_in[12];
  const float* b_ffg  = (const float*)d_in[13];
  const float* w_ffo  = (const float*)d_in[14];
  const float* b_ffo  = (const float*)d_in[15];
  const float* g_sio  = (const float*)d_in[16];
  const float* g_ffn  = (const float*)d_in[17];

  char* ws = (char*)d_ws;
  const size_t MB = 1ull << 20;
  u16*   WT_cat = (u16*)(ws + 0 * MB);      // 6 MiB  [3072][1024] (dt|lnz|yg)
  u16*   WT_y   = (u16*)(ws + 8 * MB);      // 2 MiB
  u16*   WT_ff  = (u16*)(ws + 10 * MB);     // 8 MiB  [4096][1024]
  u16*   WT_ffg = (u16*)(ws + 18 * MB);     // 8 MiB
  u16*   WT_ffo = (u16*)(ws + 26 * MB);     // 8 MiB  [1024][4096]
  float* b_cat  = (float*)(ws + 34 * MB);   // 12 KiB [3072]
  u16*   xn     = (u16*)(ws + 36 * MB);     // 32 MiB [16384][1024] bf16
  u16*   dt16   = (u16*)(ws + 68 * MB);     // 32 MiB bf16
  u16*   lnzb   = (u16*)(ws + 100 * MB);    // 32 MiB
  u16*   ygb    = (u16*)(ws + 132 * MB);    // 32 MiB
  u16*   hbf    = (u16*)(ws + 164 * MB);    // 32 MiB
  float* Pc     = (float*)(ws + 196 * MB);  // 1 MiB
  float* Sc     = (float*)(ws + 197 * MB);  // 1 MiB
  float* hin    = (float*)(ws + 198 * MB);  // 1 MiB
  u16*   gs     = (u16*)(ws + 68 * MB);     // 128 MiB overlay [16384][4096]
  // peak ws usage: 199 MiB

  float* x_out = (float*)d_out;
  float* h_out = (float*)d_out + (size_t)4 * 4096 * 1024;

  const int M = 16384, D = 1024, F = 4096;
  const dim3 tb(256);

  transpose_to_bf16<<<dim3(32, 32), tb, 0, stream>>>(w_dt, WT_cat, D, D);
  transpose_to_bf16<<<dim3(32, 32), tb, 0, stream>>>(w_ln_z, WT_cat + 1024 * 1024, D, D);
  transpose_to_bf16<<<dim3(32, 32), tb, 0, stream>>>(w_yg, WT_cat + 2 * 1024 * 1024, D, D);
  transpose_to_bf16<<<dim3(32, 32), tb, 0, stream>>>(w_y, WT_y, D, D);
  transpose_to_bf16<<<dim3(128, 32), tb, 0, stream>>>(w_ff, WT_ff, D, F);
  transpose_to_bf16<<<dim3(128, 32), tb, 0, stream>>>(w_ffg, WT_ffg, D, F);
  transpose_to_bf16<<<dim3(32, 128), tb, 0, stream>>>(w_ffo, WT_ffo, F, D);
  (void)hipMemcpyAsync(b_cat, b_dt, D * 4, hipMemcpyDeviceToDevice, stream);
  (void)hipMemcpyAsync(b_cat + 1024, b_ln_z, D * 4, hipMemcpyDeviceToDevice, stream);
  (void)hipMemcpyAsync(b_cat + 2048, b_yg, D * 4, hipMemcpyDeviceToDevice, stream);

  rmsnorm_kernel<<<M, tb, 0, stream>>>(x, g_sio, xn);

  // fused dt|lnz|yg GEMM: N=3072
  gemm256<5><<<dim3(12 * 64), 512, 0, stream>>>(xn, WT_cat, b_cat, nullptr, nullptr,
                                                nullptr, dt16, lnzb, ygb, 12, 3072, D);

  scan_pass1<<<1024, tb, 0, stream>>>(dt16, lnzb, Pc, Sc);
  scan_pass2<<<16, tb, 0, stream>>>(Pc, Sc, hidden, hin);
  scan_pass3<<<1024, tb, 0, stream>>>(dt16, lnzb, hin, h_out, hbf);

  // x1 = (h@w_y + b_y) * silu(yg) + x
  gemm256<2><<<dim3(4 * 64), 512, 0, stream>>>(hbf, WT_y, b_y, ygb, x,
                                               x_out, nullptr, nullptr, nullptr, 4, D, D);

  rmsnorm_kernel<<<M, tb, 0, stream>>>(x_out, g_ffn, xn);

  // gs = silu(xn@w_ffg + b_ffg)
  gemm256<6><<<dim3(16 * 64), 512, 0, stream>>>(xn, WT_ffg, b_ffg, nullptr, nullptr,
                                                nullptr, gs, nullptr, nullptr, 16, F, D);
  // gs = (xn@w_ff + b_ff) * gs   (in-place gated mul)
  gemm256<7><<<dim3(16 * 64), 512, 0, stream>>>(xn, WT_ff, b_ff, gs, nullptr,
                                                nullptr, gs, nullptr, nullptr, 16, F, D);
  // x_out += gs@w_ffo + b_ffo
  gemm256<4><<<dim3(4 * 64), 512, 0, stream>>>(gs, WT_ffo, b_ffo, nullptr, nullptr,
                                               x_out, nullptr, nullptr, nullptr, 4, D, F);
}

// Round 4
// 784.161 us; speedup vs baseline: 1.4055x; 1.0070x over previous
//
#include <hip/hip_runtime.h>
#include <cstdint>
#include <cstddef>

using u16 = unsigned short;
using bf16x8 = __attribute__((ext_vector_type(8))) short;
using f32x4  = __attribute__((ext_vector_type(4))) float;

__device__ __forceinline__ u16 f2bf(float f) {
  unsigned u = __float_as_uint(f);
  u += 0x7fffu + ((u >> 16) & 1u);
  return (u16)(u >> 16);
}
__device__ __forceinline__ float bf2f(u16 h) {
  return __uint_as_float(((unsigned)h) << 16);
}

__device__ __forceinline__ void gload_lds16(const void* g, void* l) {
  auto gp = reinterpret_cast<const __attribute__((address_space(1))) char*>(
      reinterpret_cast<uintptr_t>(g));
  auto lp = reinterpret_cast<__attribute__((address_space(3))) char*>(
      reinterpret_cast<uintptr_t>(l));
  __builtin_amdgcn_global_load_lds(gp, lp, 16, 0, 0);
}

// ---------- weight transpose + downcast: W f32[din][dout] -> WT bf16[dout][din]
__global__ __launch_bounds__(256) void transpose_to_bf16(
    const float* __restrict__ W, u16* __restrict__ WT, int din, int dout) {
  __shared__ float tile[32][33];
  const int j0 = blockIdx.x * 32;   // dout
  const int i0 = blockIdx.y * 32;   // din
  const int tx = threadIdx.x & 31;
  const int ty = threadIdx.x >> 5;  // 0..7
#pragma unroll
  for (int k = 0; k < 32; k += 8)
    tile[ty + k][tx] = W[(size_t)(i0 + ty + k) * dout + (j0 + tx)];
  __syncthreads();
#pragma unroll
  for (int k = 0; k < 32; k += 8)
    WT[(size_t)(j0 + ty + k) * din + (i0 + tx)] = f2bf(tile[tx][ty + k]);
}

// ---------- rmsnorm f32 -> bf16, one block per row of 1024
__global__ __launch_bounds__(256) void rmsnorm_kernel(
    const float* __restrict__ x, const float* __restrict__ g, u16* __restrict__ xn) {
  const int row = blockIdx.x;
  const float4 v = ((const float4*)(x + (size_t)row * 1024))[threadIdx.x];
  float ss = v.x * v.x + v.y * v.y + v.z * v.z + v.w * v.w;
#pragma unroll
  for (int off = 32; off > 0; off >>= 1) ss += __shfl_down(ss, off, 64);
  __shared__ float red[4];
  if ((threadIdx.x & 63) == 0) red[threadIdx.x >> 6] = ss;
  __syncthreads();
  const float rs = rsqrtf((red[0] + red[1] + red[2] + red[3]) * (1.f / 1024.f) + 1e-6f);
  const float4 gv = ((const float4*)g)[threadIdx.x];
  ushort4 o;
  o.x = f2bf(v.x * rs * gv.x);
  o.y = f2bf(v.y * rs * gv.y);
  o.z = f2bf(v.z * rs * gv.z);
  o.w = f2bf(v.w * rs * gv.w);
  ((ushort4*)(xn + (size_t)row * 1024))[threadIdx.x] = o;
}

// ---------- chunked linear-recurrence scan: h[l] = sig(-dt)*h[l-1] + sig(dt)*sig(lnz)
__global__ __launch_bounds__(256) void scan_pass1(
    const u16* __restrict__ dt, const u16* __restrict__ lnz,
    float* __restrict__ P, float* __restrict__ S) {
  const int blk = blockIdx.x;              // B*64*4 = 1024 blocks
  const int dblk = blk & 3;
  const int chunk = (blk >> 2) & 63;
  const int b = blk >> 8;
  const int d = dblk * 256 + threadIdx.x;
  const size_t base = ((size_t)b * 4096 + (size_t)chunk * 64) * 1024 + d;
  float p = 1.f, s = 0.f;
#pragma unroll 8
  for (int l = 0; l < 64; ++l) {
    const float dtv = bf2f(dt[base + (size_t)l * 1024]);
    const float zv = bf2f(lnz[base + (size_t)l * 1024]);
    const float a = 1.f / (1.f + __expf(dtv));        // sigmoid(-dt)
    const float zs = 1.f / (1.f + __expf(-zv));       // sigmoid(lnz_pre)
    const float in = (1.f - a) * zs;
    p *= a;
    s = a * s + in;
  }
  const size_t o = ((size_t)b * 64 + chunk) * 1024 + d;
  P[o] = p;
  S[o] = s;
}

__global__ __launch_bounds__(256) void scan_pass2(
    const float* __restrict__ P, const float* __restrict__ S,
    const float* __restrict__ hidden, float* __restrict__ hin) {
  const int idx = blockIdx.x * 256 + threadIdx.x;  // 0..4095
  const int b = idx >> 10, d = idx & 1023;
  float h = hidden[idx];
#pragma unroll 8
  for (int c = 0; c < 64; ++c) {
    const size_t o = ((size_t)b * 64 + c) * 1024 + d;
    hin[o] = h;
    h = P[o] * h + S[o];
  }
}

__global__ __launch_bounds__(256) void scan_pass3(
    const u16* __restrict__ dt, const u16* __restrict__ lnz,
    const float* __restrict__ hin, float* __restrict__ h_out, u16* __restrict__ hbf) {
  const int blk = blockIdx.x;
  const int dblk = blk & 3;
  const int chunk = (blk >> 2) & 63;
  const int b = blk >> 8;
  const int d = dblk * 256 + threadIdx.x;
  const size_t base = ((size_t)b * 4096 + (size_t)chunk * 64) * 1024 + d;
  float h = hin[((size_t)b * 64 + chunk) * 1024 + d];
#pragma unroll 4
  for (int l = 0; l < 64; ++l) {
    const float dtv = bf2f(dt[base + (size_t)l * 1024]);
    const float zv = bf2f(lnz[base + (size_t)l * 1024]);
    const float a = 1.f / (1.f + __expf(dtv));
    const float zs = 1.f / (1.f + __expf(-zv));
    h = a * h + (1.f - a) * zs;
    h_out[base + (size_t)l * 1024] = h;
    hbf[base + (size_t)l * 1024] = f2bf(h);
  }
}

// ---------- 256x256 8-phase GEMM: C[M][N] = A[M][K] @ B^T, B stored [N][K] bf16.
// 8 waves (2Mx4N), per-wave 128x64 out, BK=64, ring of 10 half-tile LDS slots
// (160 KiB), prefetch lead = 3 half-tiles, counted vmcnt(6), raw s_barrier,
// setprio around MFMA.
// Ring audit: writes during tile t hit slots of halves {4t-3..4t}; only 4t
// (tile t A0) is live, and its last reads (ph2) are lgkm-drained before the
// ph2 trailing barrier, which orders them before the ph3 stage that overwrites.
// EPI: 5 = fused3: bf16 outs {outH=dt, outH2=lnz, outH3=yg}, row stride 1024
//      2 = f32 out = (acc+b)*silu(gate bf16) + resid
//      6 = bf16 out = silu(acc+b)
//      7 = bf16 out = (acc+b)*bf2f(gate)   (gate may alias outH: in-place)
//      4 = f32 out = acc + b + outF (in-place residual add)
template <int EPI>
__global__ __launch_bounds__(512) void gemm256(
    const u16* __restrict__ A, const u16* __restrict__ B,
    const float* __restrict__ bias, const u16* __restrict__ gate,
    const float* __restrict__ resid, float* __restrict__ outF,
    u16* __restrict__ outH, u16* __restrict__ outH2, u16* __restrict__ outH3,
    int ntx, int N, int K) {
  const int tid = threadIdx.x;
  const int lane = tid & 63;
  const int wid = tid >> 6;
  const int wr = wid >> 2;   // 0..1 -> A half
  const int wc = wid & 3;    // 0..3 -> 64-col strip; wc>>1 -> B half

  // XCD-aware swizzle (grid %8==0 for all our launches)
  const int nwg = gridDim.x;
  int id = blockIdx.x;
  id = (id & 7) * (nwg >> 3) + (id >> 3);
  const int m0 = (id / ntx) * 256;
  const int n0 = (id % ntx) * 256;

  __shared__ __align__(16) char lds[10 * 16384];

  f32x4 acc[8][4];
#pragma unroll
  for (int m = 0; m < 8; ++m)
#pragma unroll
    for (int n = 0; n < 4; ++n) acc[m][n] = (f32x4){0.f, 0.f, 0.f, 0.f};

  bf16x8 aR[4][2], bR[4][2];

  const int NT = K >> 6;
  const int HT = NT << 2;

  // half-tile h: tile t=h>>2, part h&3: 0=A rows[0..127], 1=A rows[128..255],
  // 2=B rows[0..127], 3=B rows[128..255]. slot = h%10 -> 16 KiB each.
  auto stage = [&](int h) {
    if (h >= HT) return;
    const int slot = h % 10;
    const int part = h & 3;
    const int kt = h >> 2;
    const u16* src = (part < 2) ? A : B;
    const int r0 = ((part < 2) ? m0 : n0) + (part & 1) * 128;
    char* base = lds + slot * 16384;
#pragma unroll
    for (int i = 0; i < 2; ++i) {
      const int f = (tid + i * 512) * 16;            // 16 KiB over 512 thr x2
      const int row = f >> 7;                        // 128 B per row
      const int kb = (f & 127) ^ ((row & 7) << 4);   // inverse swizzle on src
      gload_lds16((const char*)(src + (size_t)(r0 + row) * K + kt * 64) + kb, base + f);
    }
  };

#define READA(SLOT, QM)                                                        \
  {                                                                            \
    const char* _b = lds + (SLOT) * 16384;                                     \
    _Pragma("unroll") for (int m = 0; m < 4; ++m) {                            \
      const int hr = (QM) * 64 + m * 16 + (lane & 15);                         \
      _Pragma("unroll") for (int k = 0; k < 2; ++k) {                          \
        aR[m][k] = *(const bf16x8*)(_b + hr * 128 +                            \
                    ((k * 64 + ((lane >> 4) << 4)) ^ ((hr & 7) << 4)));        \
      }                                                                        \
    }                                                                          \
  }

#define READB(SLOT, NP)                                                        \
  {                                                                            \
    const char* _b = lds + (SLOT) * 16384;                                     \
    _Pragma("unroll") for (int n = 0; n < 2; ++n) {                            \
      const int hr = (wc & 1) * 64 + ((NP) + n) * 16 + (lane & 15);            \
      _Pragma("unroll") for (int k = 0; k < 2; ++k) {                          \
        bR[(NP) + n][k] = *(const bf16x8*)(_b + hr * 128 +                     \
                    ((k * 64 + ((lane >> 4) << 4)) ^ ((hr & 7) << 4)));        \
      }                                                                        \
    }                                                                          \
  }

#define MMAQ(QM, QN)                                                           \
  __builtin_amdgcn_s_setprio(1);                                               \
  _Pragma("unroll") for (int m = 0; m < 4; ++m)                                \
  _Pragma("unroll") for (int n = 0; n < 2; ++n)                                \
  _Pragma("unroll") for (int k = 0; k < 2; ++k)                                \
      acc[(QM) * 4 + m][(QN) * 2 + n] = __builtin_amdgcn_mfma_f32_16x16x32_bf16( \
          aR[m][k], bR[(QN) * 2 + n][k], acc[(QM) * 4 + m][(QN) * 2 + n], 0, 0, 0); \
  __builtin_amdgcn_s_setprio(0);

  // prologue: stage halves 0..6 (tile0 complete + tile1 A0,A1,B0)
#pragma unroll
  for (int h = 0; h < 7; ++h) stage(h);
  asm volatile("s_waitcnt vmcnt(6)" ::: "memory");   // tile0 resident, 3 stages in flight
  __builtin_amdgcn_s_barrier();

  for (int t = 0; t < NT; ++t) {
    const int sA = (4 * t + wr) % 10;
    const int sB = (4 * t + 2 + (wc >> 1)) % 10;
    const int hb = 4 * t + 7;
    // phase 0: A(qm0) 8 reads + B(n0,1) 4 reads; stage t+1 B1
    READA(sA, 0);
    READB(sB, 0);
    stage(hb);
    __builtin_amdgcn_s_barrier();
    MMAQ(0, 0);
    __builtin_amdgcn_s_barrier();
    // phase 1: B(n2,3) 4 reads; stage t+2 A0
    READB(sB, 2);
    stage(hb + 1);
    __builtin_amdgcn_s_barrier();
    MMAQ(0, 1);
    __builtin_amdgcn_s_barrier();
    // phase 2: A(qm1) 8 reads; stage t+2 A1
    READA(sA, 1);
    stage(hb + 2);
    __builtin_amdgcn_s_barrier();
    MMAQ(1, 0);
    __builtin_amdgcn_s_barrier();
    // phase 3: stage t+2 B0; counted vmcnt -> tile t+1 fully staged
    stage(hb + 3);
    __builtin_amdgcn_s_barrier();
    MMAQ(1, 1);
    if (t < NT - 2) asm volatile("s_waitcnt vmcnt(6)" ::: "memory");
    else            asm volatile("s_waitcnt vmcnt(0)" ::: "memory");
    __builtin_amdgcn_s_barrier();
  }

  // epilogue: C/D layout col = lane&15, row = (lane>>4)*4 + j
#pragma unroll
  for (int m = 0; m < 8; ++m) {
#pragma unroll
    for (int n = 0; n < 4; ++n) {
      const int col = n0 + wc * 64 + n * 16 + (lane & 15);
#pragma unroll
      for (int j = 0; j < 4; ++j) {
        const int row = m0 + wr * 128 + m * 16 + ((lane >> 4) << 2) + j;
        const float v = acc[m][n][j] + bias[col];
        if constexpr (EPI == 5) {
          const int rg = col >> 10;                     // block-uniform
          const size_t o = (size_t)row * 1024 + (col & 1023);
          if (rg == 0) outH[o] = f2bf(v);
          else if (rg == 1) outH2[o] = f2bf(v);
          else outH3[o] = f2bf(v);
        } else {
          const size_t o = (size_t)row * N + col;
          if constexpr (EPI == 2) {
            const float gt = bf2f(gate[o]);
            outF[o] = v * (gt / (1.f + __expf(-gt))) + resid[o];
          } else if constexpr (EPI == 6) {
            outH[o] = f2bf(v / (1.f + __expf(-v)));
          } else if constexpr (EPI == 7) {
            outH[o] = f2bf(v * bf2f(gate[o]));          // gate==outH ok (RAW per elem)
          } else if constexpr (EPI == 4) {
            outF[o] = v + outF[o];
          }
        }
      }
    }
  }
#undef READA
#undef READB
#undef MMAQ
}

extern "C" void kernel_launch(void* const* d_in, const int* in_sizes, int n_in,
                              void* d_out, int out_size, void* d_ws, size_t ws_size,
                              hipStream_t stream) {
  const float* x      = (const float*)d_in[0];
  const float* hidden = (const float*)d_in[1];
  const float* w_ln_z = (const float*)d_in[2];
  const float* b_ln_z = (const float*)d_in[3];
  const float* w_dt   = (const float*)d_in[4];
  const float* b_dt   = (const float*)d_in[5];
  const float* w_y    = (const float*)d_in[6];
  const float* b_y    = (const float*)d_in[7];
  const float* w_yg   = (const float*)d_in[8];
  const float* b_yg   = (const float*)d_in[9];
  const float* w_ff   = (const float*)d_in[10];
  const float* b_ff   = (const float*)d_in[11];
  const float* w_ffg  = (const float*)d_in[12];
  const float* b_ffg  = (const float*)d_in[13];
  const float* w_ffo  = (const float*)d_in[14];
  const float* b_ffo  = (const float*)d_in[15];
  const float* g_sio  = (const float*)d_in[16];
  const float* g_ffn  = (const float*)d_in[17];

  char* ws = (char*)d_ws;
  const size_t MB = 1ull << 20;
  u16*   WT_cat = (u16*)(ws + 0 * MB);      // 6 MiB  [3072][1024] (dt|lnz|yg)
  u16*   WT_y   = (u16*)(ws + 8 * MB);      // 2 MiB
  u16*   WT_ff  = (u16*)(ws + 10 * MB);     // 8 MiB  [4096][1024]
  u16*   WT_ffg = (u16*)(ws + 18 * MB);     // 8 MiB
  u16*   WT_ffo = (u16*)(ws + 26 * MB);     // 8 MiB  [1024][4096]
  float* b_cat  = (float*)(ws + 34 * MB);   // 12 KiB [3072]
  u16*   xn     = (u16*)(ws + 36 * MB);     // 32 MiB [16384][1024] bf16
  u16*   dt16   = (u16*)(ws + 68 * MB);     // 32 MiB bf16
  u16*   lnzb   = (u16*)(ws + 100 * MB);    // 32 MiB
  u16*   ygb    = (u16*)(ws + 132 * MB);    // 32 MiB
  u16*   hbf    = (u16*)(ws + 164 * MB);    // 32 MiB
  float* Pc     = (float*)(ws + 196 * MB);  // 1 MiB
  float* Sc     = (float*)(ws + 197 * MB);  // 1 MiB
  float* hin    = (float*)(ws + 198 * MB);  // 1 MiB
  u16*   gs     = (u16*)(ws + 68 * MB);     // 128 MiB overlay [16384][4096]
  // peak ws usage: 199 MiB

  float* x_out = (float*)d_out;
  float* h_out = (float*)d_out + (size_t)4 * 4096 * 1024;

  const int M = 16384, D = 1024, F = 4096;
  const dim3 tb(256);

  transpose_to_bf16<<<dim3(32, 32), tb, 0, stream>>>(w_dt, WT_cat, D, D);
  transpose_to_bf16<<<dim3(32, 32), tb, 0, stream>>>(w_ln_z, WT_cat + 1024 * 1024, D, D);
  transpose_to_bf16<<<dim3(32, 32), tb, 0, stream>>>(w_yg, WT_cat + 2 * 1024 * 1024, D, D);
  transpose_to_bf16<<<dim3(32, 32), tb, 0, stream>>>(w_y, WT_y, D, D);
  transpose_to_bf16<<<dim3(128, 32), tb, 0, stream>>>(w_ff, WT_ff, D, F);
  transpose_to_bf16<<<dim3(128, 32), tb, 0, stream>>>(w_ffg, WT_ffg, D, F);
  transpose_to_bf16<<<dim3(32, 128), tb, 0, stream>>>(w_ffo, WT_ffo, F, D);
  (void)hipMemcpyAsync(b_cat, b_dt, D * 4, hipMemcpyDeviceToDevice, stream);
  (void)hipMemcpyAsync(b_cat + 1024, b_ln_z, D * 4, hipMemcpyDeviceToDevice, stream);
  (void)hipMemcpyAsync(b_cat + 2048, b_yg, D * 4, hipMemcpyDeviceToDevice, stream);

  rmsnorm_kernel<<<M, tb, 0, stream>>>(x, g_sio, xn);

  // fused dt|lnz|yg GEMM: N=3072
  gemm256<5><<<dim3(12 * 64), 512, 0, stream>>>(xn, WT_cat, b_cat, nullptr, nullptr,
                                                nullptr, dt16, lnzb, ygb, 12, 3072, D);

  scan_pass1<<<1024, tb, 0, stream>>>(dt16, lnzb, Pc, Sc);
  scan_pass2<<<16, tb, 0, stream>>>(Pc, Sc, hidden, hin);
  scan_pass3<<<1024, tb, 0, stream>>>(dt16, lnzb, hin, h_out, hbf);

  // x1 = (h@w_y + b_y) * silu(yg) + x
  gemm256<2><<<dim3(4 * 64), 512, 0, stream>>>(hbf, WT_y, b_y, ygb, x,
                                               x_out, nullptr, nullptr, nullptr, 4, D, D);

  rmsnorm_kernel<<<M, tb, 0, stream>>>(x_out, g_ffn, xn);

  // gs = silu(xn@w_ffg + b_ffg)
  gemm256<6><<<dim3(16 * 64), 512, 0, stream>>>(xn, WT_ffg, b_ffg, nullptr, nullptr,
                                                nullptr, gs, nullptr, nullptr, 16, F, D);
  // gs = (xn@w_ff + b_ff) * gs   (in-place gated mul)
  gemm256<7><<<dim3(16 * 64), 512, 0, stream>>>(xn, WT_ff, b_ff, gs, nullptr,
                                                nullptr, gs, nullptr, nullptr, 16, F, D);
  // x_out += gs@w_ffo + b_ffo
  gemm256<4><<<dim3(4 * 64), 512, 0, stream>>>(gs, WT_ffo, b_ffo, nullptr, nullptr,
                                               x_out, nullptr, nullptr, nullptr, 4, D, F);
}

// Round 5
// 779.507 us; speedup vs baseline: 1.4139x; 1.0060x over previous
//
#include <hip/hip_runtime.h>
#include <cstdint>
#include <cstddef>

using u16 = unsigned short;
using bf16x8 = __attribute__((ext_vector_type(8))) short;
using f32x4  = __attribute__((ext_vector_type(4))) float;

__device__ __forceinline__ u16 f2bf(float f) {
  unsigned u = __float_as_uint(f);
  u += 0x7fffu + ((u >> 16) & 1u);
  return (u16)(u >> 16);
}
__device__ __forceinline__ float bf2f(u16 h) {
  return __uint_as_float(((unsigned)h) << 16);
}

__device__ __forceinline__ void gload_lds16(const void* g, void* l) {
  auto gp = reinterpret_cast<const __attribute__((address_space(1))) char*>(
      reinterpret_cast<uintptr_t>(g));
  auto lp = reinterpret_cast<__attribute__((address_space(3))) char*>(
      reinterpret_cast<uintptr_t>(l));
  __builtin_amdgcn_global_load_lds(gp, lp, 16, 0, 0);
}

// ---------- weight transpose + downcast: W f32[din][dout] -> WT bf16[dout][din]
__global__ __launch_bounds__(256) void transpose_to_bf16(
    const float* __restrict__ W, u16* __restrict__ WT, int din, int dout) {
  __shared__ float tile[32][33];
  const int j0 = blockIdx.x * 32;   // dout
  const int i0 = blockIdx.y * 32;   // din
  const int tx = threadIdx.x & 31;
  const int ty = threadIdx.x >> 5;  // 0..7
#pragma unroll
  for (int k = 0; k < 32; k += 8)
    tile[ty + k][tx] = W[(size_t)(i0 + ty + k) * dout + (j0 + tx)];
  __syncthreads();
#pragma unroll
  for (int k = 0; k < 32; k += 8)
    WT[(size_t)(j0 + ty + k) * din + (i0 + tx)] = f2bf(tile[tx][ty + k]);
}

// ---------- rmsnorm f32 -> bf16, one block per row of 1024
__global__ __launch_bounds__(256) void rmsnorm_kernel(
    const float* __restrict__ x, const float* __restrict__ g, u16* __restrict__ xn) {
  const int row = blockIdx.x;
  const float4 v = ((const float4*)(x + (size_t)row * 1024))[threadIdx.x];
  float ss = v.x * v.x + v.y * v.y + v.z * v.z + v.w * v.w;
#pragma unroll
  for (int off = 32; off > 0; off >>= 1) ss += __shfl_down(ss, off, 64);
  __shared__ float red[4];
  if ((threadIdx.x & 63) == 0) red[threadIdx.x >> 6] = ss;
  __syncthreads();
  const float rs = rsqrtf((red[0] + red[1] + red[2] + red[3]) * (1.f / 1024.f) + 1e-6f);
  const float4 gv = ((const float4*)g)[threadIdx.x];
  ushort4 o;
  o.x = f2bf(v.x * rs * gv.x);
  o.y = f2bf(v.y * rs * gv.y);
  o.z = f2bf(v.z * rs * gv.z);
  o.w = f2bf(v.w * rs * gv.w);
  ((ushort4*)(xn + (size_t)row * 1024))[threadIdx.x] = o;
}

// ---------- chunked linear-recurrence scan: h[l] = sig(-dt)*h[l-1] + sig(dt)*sig(lnz)
__global__ __launch_bounds__(256) void scan_pass1(
    const u16* __restrict__ dt, const u16* __restrict__ lnz,
    float* __restrict__ P, float* __restrict__ S) {
  const int blk = blockIdx.x;              // B*64*4 = 1024 blocks
  const int dblk = blk & 3;
  const int chunk = (blk >> 2) & 63;
  const int b = blk >> 8;
  const int d = dblk * 256 + threadIdx.x;
  const size_t base = ((size_t)b * 4096 + (size_t)chunk * 64) * 1024 + d;
  float p = 1.f, s = 0.f;
#pragma unroll 8
  for (int l = 0; l < 64; ++l) {
    const float dtv = bf2f(dt[base + (size_t)l * 1024]);
    const float zv = bf2f(lnz[base + (size_t)l * 1024]);
    const float a = 1.f / (1.f + __expf(dtv));        // sigmoid(-dt)
    const float zs = 1.f / (1.f + __expf(-zv));       // sigmoid(lnz_pre)
    const float in = (1.f - a) * zs;
    p *= a;
    s = a * s + in;
  }
  const size_t o = ((size_t)b * 64 + chunk) * 1024 + d;
  P[o] = p;
  S[o] = s;
}

__global__ __launch_bounds__(256) void scan_pass2(
    const float* __restrict__ P, const float* __restrict__ S,
    const float* __restrict__ hidden, float* __restrict__ hin) {
  const int idx = blockIdx.x * 256 + threadIdx.x;  // 0..4095
  const int b = idx >> 10, d = idx & 1023;
  float h = hidden[idx];
#pragma unroll 8
  for (int c = 0; c < 64; ++c) {
    const size_t o = ((size_t)b * 64 + c) * 1024 + d;
    hin[o] = h;
    h = P[o] * h + S[o];
  }
}

__global__ __launch_bounds__(256) void scan_pass3(
    const u16* __restrict__ dt, const u16* __restrict__ lnz,
    const float* __restrict__ hin, float* __restrict__ h_out, u16* __restrict__ hbf) {
  const int blk = blockIdx.x;
  const int dblk = blk & 3;
  const int chunk = (blk >> 2) & 63;
  const int b = blk >> 8;
  const int d = dblk * 256 + threadIdx.x;
  const size_t base = ((size_t)b * 4096 + (size_t)chunk * 64) * 1024 + d;
  float h = hin[((size_t)b * 64 + chunk) * 1024 + d];
#pragma unroll 4
  for (int l = 0; l < 64; ++l) {
    const float dtv = bf2f(dt[base + (size_t)l * 1024]);
    const float zv = bf2f(lnz[base + (size_t)l * 1024]);
    const float a = 1.f / (1.f + __expf(dtv));
    const float zs = 1.f / (1.f + __expf(-zv));
    h = a * h + (1.f - a) * zs;
    h_out[base + (size_t)l * 1024] = h;
    hbf[base + (size_t)l * 1024] = f2bf(h);
  }
}

// ---------- 256x256 8-phase GEMM: C[M][N] = A[M][K] @ B^T, B stored [N][K] bf16.
// 8 waves (2Mx4N), per-wave 128x64 out, BK=64, ring of 10 half-tile LDS slots
// (160 KiB), prefetch lead = 3 half-tiles, counted vmcnt(6), raw s_barrier,
// setprio around MFMA. ALL addressing hoisted out of the K-loop:
//  - 12 precomputed LDS read offsets (QM adds +8192 imm, NP adds +2048*NP imm
//    since the XOR swizzle term depends only on hr&7, invariant under +16/+32/+64)
//  - slot bases kept as incremental ints, readfirstlane'd to SGPR
//  - stage addresses are 4 persistent per-thread byte pointers advanced +128/tile;
//    second gload of each half-tile at ptr + 128*K (row+64, same swizzle byte)
// EPI: 5 = fused3: bf16 outs {outH=dt, outH2=lnz, outH3=yg}, row stride 1024
//      2 = f32 out = (acc+b)*silu(gate bf16) + resid
//      6 = bf16 out = silu(acc+b)
//      7 = bf16 out = (acc+b)*bf2f(gate)   (gate may alias outH: in-place)
//      4 = f32 out = acc + b + outF (in-place residual add)
template <int EPI>
__global__ __launch_bounds__(512) void gemm256(
    const u16* __restrict__ A, const u16* __restrict__ B,
    const float* __restrict__ bias, const u16* __restrict__ gate,
    const float* __restrict__ resid, float* __restrict__ outF,
    u16* __restrict__ outH, u16* __restrict__ outH2, u16* __restrict__ outH3,
    int ntx, int N, int K) {
  constexpr int SLOT = 16384;
  constexpr int LDSZ = 10 * SLOT;
  const int tid = threadIdx.x;
  const int lane = tid & 63;
  const int wid = tid >> 6;
  const int wr = wid >> 2;   // 0..1 -> A half
  const int wc = wid & 3;    // 0..3 -> 64-col strip; wc>>1 -> B half

  // XCD-aware swizzle (grid %8==0 for all our launches)
  const int nwg = gridDim.x;
  int id = blockIdx.x;
  id = (id & 7) * (nwg >> 3) + (id >> 3);
  const int m0 = (id / ntx) * 256;
  const int n0 = (id % ntx) * 256;

  __shared__ __align__(16) char lds[LDSZ];

  f32x4 acc[8][4];
#pragma unroll
  for (int m = 0; m < 8; ++m)
#pragma unroll
    for (int n = 0; n < 4; ++n) acc[m][n] = (f32x4){0.f, 0.f, 0.f, 0.f};

  bf16x8 aR[4][2], bR[4][2];

  // ---- hoisted LDS read offsets (relative to slot base) ----
  int aOff[4][2], bOff[2][2];
  {
    const int lq = (lane >> 4) << 4;
#pragma unroll
    for (int m = 0; m < 4; ++m) {
      const int hr = m * 16 + (lane & 15);
#pragma unroll
      for (int k = 0; k < 2; ++k)
        aOff[m][k] = hr * 128 + ((k * 64 + lq) ^ ((hr & 7) << 4));
    }
#pragma unroll
    for (int n = 0; n < 2; ++n) {
      const int hr = (wc & 1) * 64 + n * 16 + (lane & 15);
#pragma unroll
      for (int k = 0; k < 2; ++k)
        bOff[n][k] = hr * 128 + ((k * 64 + lq) ^ ((hr & 7) << 4));
    }
  }

  // ---- hoisted stage addressing ----
  const int row0 = tid >> 3;                               // 0..63
  const int kb0  = ((tid & 7) * 16) ^ ((row0 & 7) << 4);   // inverse-swizzled src byte
  const size_t dRow = (size_t)128 * K;                     // +64 rows (bytes)
  const char* pA0 = (const char*)A + (size_t)(m0 + row0) * K * 2 + kb0;
  const char* pA1 = pA0 + (size_t)256 * K;                 // +128 rows
  const char* pB0 = (const char*)B + (size_t)(n0 + row0) * K * 2 + kb0;
  const char* pB1 = pB0 + (size_t)256 * K;
  const int ldst = tid * 16;                               // LDS offset within slot

#define STAGE(PTR, SB)                                                        \
  {                                                                           \
    gload_lds16(PTR, lds + (SB) + ldst);                                      \
    gload_lds16(PTR + dRow, lds + (SB) + ldst + 8192);                        \
    PTR += 128;                                                               \
  }

#define READA(SAB, QM)                                                        \
  _Pragma("unroll") for (int m = 0; m < 4; ++m)                               \
  _Pragma("unroll") for (int k = 0; k < 2; ++k)                               \
    aR[m][k] = *(const bf16x8*)(lds + (SAB) + aOff[m][k] + (QM) * 8192);

#define READB(SBB, NP)                                                        \
  _Pragma("unroll") for (int n = 0; n < 2; ++n)                               \
  _Pragma("unroll") for (int k = 0; k < 2; ++k)                               \
    bR[(NP) + n][k] = *(const bf16x8*)(lds + (SBB) + bOff[n][k] + (NP) * 2048);

#define MMAQ(QM, QN)                                                          \
  __builtin_amdgcn_s_setprio(1);                                              \
  _Pragma("unroll") for (int m = 0; m < 4; ++m)                               \
  _Pragma("unroll") for (int n = 0; n < 2; ++n)                               \
  _Pragma("unroll") for (int k = 0; k < 2; ++k)                               \
      acc[(QM) * 4 + m][(QN) * 2 + n] = __builtin_amdgcn_mfma_f32_16x16x32_bf16( \
          aR[m][k], bR[(QN) * 2 + n][k], acc[(QM) * 4 + m][(QN) * 2 + n], 0, 0, 0); \
  __builtin_amdgcn_s_setprio(0);

  const int NT = K >> 6;

  // prologue: halves 0..6 -> slots 0..6 (tile0 complete + tile1 A0,A1,B0)
  STAGE(pA0, 0 * SLOT);
  STAGE(pA1, 1 * SLOT);
  STAGE(pB0, 2 * SLOT);
  STAGE(pB1, 3 * SLOT);
  STAGE(pA0, 4 * SLOT);
  STAGE(pA1, 5 * SLOT);
  STAGE(pB0, 6 * SLOT);
  asm volatile("s_waitcnt vmcnt(6)" ::: "memory");   // tile0 resident, 3 halves in flight
  __builtin_amdgcn_s_barrier();

  int iA = wr;             // slot of this wave's A half, advances +4 mod 10
  int iB = 2 + (wc >> 1);  // slot of this wave's B half
  int iS = 7;              // stage slot for phase 0

  for (int t = 0; t < NT; ++t) {
    const int sAb = __builtin_amdgcn_readfirstlane(iA * SLOT);
    const int sBb = __builtin_amdgcn_readfirstlane(iB * SLOT);
    int s0 = iS * SLOT;
    int s1 = s0 + SLOT; if (s1 >= LDSZ) s1 -= LDSZ;
    int s2 = s1 + SLOT; if (s2 >= LDSZ) s2 -= LDSZ;
    int s3 = s2 + SLOT; if (s3 >= LDSZ) s3 -= LDSZ;
    const bool st0 = (t <= NT - 2);     // stage B1 of tile t+1
    const bool st123 = (t <= NT - 3);   // stage A0/A1/B0 of tile t+2
    // phase 0
    READA(sAb, 0);
    READB(sBb, 0);
    if (st0) STAGE(pB1, s0);
    __builtin_amdgcn_s_barrier();
    MMAQ(0, 0);
    __builtin_amdgcn_s_barrier();
    // phase 1
    READB(sBb, 2);
    if (st123) STAGE(pA0, s1);
    __builtin_amdgcn_s_barrier();
    MMAQ(0, 1);
    __builtin_amdgcn_s_barrier();
    // phase 2
    READA(sAb, 1);
    if (st123) STAGE(pA1, s2);
    __builtin_amdgcn_s_barrier();
    MMAQ(1, 0);
    __builtin_amdgcn_s_barrier();
    // phase 3
    if (st123) STAGE(pB0, s3);
    __builtin_amdgcn_s_barrier();
    MMAQ(1, 1);
    if (t < NT - 2) asm volatile("s_waitcnt vmcnt(6)" ::: "memory");
    else            asm volatile("s_waitcnt vmcnt(0)" ::: "memory");
    __builtin_amdgcn_s_barrier();
    iA += 4; if (iA >= 10) iA -= 10;
    iB += 4; if (iB >= 10) iB -= 10;
    iS += 4; if (iS >= 10) iS -= 10;
  }

  // epilogue: C/D layout col = lane&15, row = (lane>>4)*4 + j
#pragma unroll
  for (int m = 0; m < 8; ++m) {
#pragma unroll
    for (int n = 0; n < 4; ++n) {
      const int col = n0 + wc * 64 + n * 16 + (lane & 15);
#pragma unroll
      for (int j = 0; j < 4; ++j) {
        const int row = m0 + wr * 128 + m * 16 + ((lane >> 4) << 2) + j;
        const float v = acc[m][n][j] + bias[col];
        if constexpr (EPI == 5) {
          const int rg = col >> 10;                     // block-uniform
          const size_t o = (size_t)row * 1024 + (col & 1023);
          if (rg == 0) outH[o] = f2bf(v);
          else if (rg == 1) outH2[o] = f2bf(v);
          else outH3[o] = f2bf(v);
        } else {
          const size_t o = (size_t)row * N + col;
          if constexpr (EPI == 2) {
            const float gt = bf2f(gate[o]);
            outF[o] = v * (gt / (1.f + __expf(-gt))) + resid[o];
          } else if constexpr (EPI == 6) {
            outH[o] = f2bf(v / (1.f + __expf(-v)));
          } else if constexpr (EPI == 7) {
            outH[o] = f2bf(v * bf2f(gate[o]));          // gate==outH ok (RAW per elem)
          } else if constexpr (EPI == 4) {
            outF[o] = v + outF[o];
          }
        }
      }
    }
  }
#undef STAGE
#undef READA
#undef READB
#undef MMAQ
}

extern "C" void kernel_launch(void* const* d_in, const int* in_sizes, int n_in,
                              void* d_out, int out_size, void* d_ws, size_t ws_size,
                              hipStream_t stream) {
  const float* x      = (const float*)d_in[0];
  const float* hidden = (const float*)d_in[1];
  const float* w_ln_z = (const float*)d_in[2];
  const float* b_ln_z = (const float*)d_in[3];
  const float* w_dt   = (const float*)d_in[4];
  const float* b_dt   = (const float*)d_in[5];
  const float* w_y    = (const float*)d_in[6];
  const float* b_y    = (const float*)d_in[7];
  const float* w_yg   = (const float*)d_in[8];
  const float* b_yg   = (const float*)d_in[9];
  const float* w_ff   = (const float*)d_in[10];
  const float* b_ff   = (const float*)d_in[11];
  const float* w_ffg  = (const float*)d_in[12];
  const float* b_ffg  = (const float*)d_in[13];
  const float* w_ffo  = (const float*)d_in[14];
  const float* b_ffo  = (const float*)d_in[15];
  const float* g_sio  = (const float*)d_in[16];
  const float* g_ffn  = (const float*)d_in[17];

  char* ws = (char*)d_ws;
  const size_t MB = 1ull << 20;
  u16*   WT_cat = (u16*)(ws + 0 * MB);      // 6 MiB  [3072][1024] (dt|lnz|yg)
  u16*   WT_y   = (u16*)(ws + 8 * MB);      // 2 MiB
  u16*   WT_ff  = (u16*)(ws + 10 * MB);     // 8 MiB  [4096][1024]
  u16*   WT_ffg = (u16*)(ws + 18 * MB);     // 8 MiB
  u16*   WT_ffo = (u16*)(ws + 26 * MB);     // 8 MiB  [1024][4096]
  float* b_cat  = (float*)(ws + 34 * MB);   // 12 KiB [3072]
  u16*   xn     = (u16*)(ws + 36 * MB);     // 32 MiB [16384][1024] bf16
  u16*   dt16   = (u16*)(ws + 68 * MB);     // 32 MiB bf16
  u16*   lnzb   = (u16*)(ws + 100 * MB);    // 32 MiB
  u16*   ygb    = (u16*)(ws + 132 * MB);    // 32 MiB
  u16*   hbf    = (u16*)(ws + 164 * MB);    // 32 MiB
  float* Pc     = (float*)(ws + 196 * MB);  // 1 MiB
  float* Sc     = (float*)(ws + 197 * MB);  // 1 MiB
  float* hin    = (float*)(ws + 198 * MB);  // 1 MiB
  u16*   gs     = (u16*)(ws + 68 * MB);     // 128 MiB overlay [16384][4096]
  // peak ws usage: 199 MiB

  float* x_out = (float*)d_out;
  float* h_out = (float*)d_out + (size_t)4 * 4096 * 1024;

  const int M = 16384, D = 1024, F = 4096;
  const dim3 tb(256);

  transpose_to_bf16<<<dim3(32, 32), tb, 0, stream>>>(w_dt, WT_cat, D, D);
  transpose_to_bf16<<<dim3(32, 32), tb, 0, stream>>>(w_ln_z, WT_cat + 1024 * 1024, D, D);
  transpose_to_bf16<<<dim3(32, 32), tb, 0, stream>>>(w_yg, WT_cat + 2 * 1024 * 1024, D, D);
  transpose_to_bf16<<<dim3(32, 32), tb, 0, stream>>>(w_y, WT_y, D, D);
  transpose_to_bf16<<<dim3(128, 32), tb, 0, stream>>>(w_ff, WT_ff, D, F);
  transpose_to_bf16<<<dim3(128, 32), tb, 0, stream>>>(w_ffg, WT_ffg, D, F);
  transpose_to_bf16<<<dim3(32, 128), tb, 0, stream>>>(w_ffo, WT_ffo, F, D);
  (void)hipMemcpyAsync(b_cat, b_dt, D * 4, hipMemcpyDeviceToDevice, stream);
  (void)hipMemcpyAsync(b_cat + 1024, b_ln_z, D * 4, hipMemcpyDeviceToDevice, stream);
  (void)hipMemcpyAsync(b_cat + 2048, b_yg, D * 4, hipMemcpyDeviceToDevice, stream);

  rmsnorm_kernel<<<M, tb, 0, stream>>>(x, g_sio, xn);

  // fused dt|lnz|yg GEMM: N=3072
  gemm256<5><<<dim3(12 * 64), 512, 0, stream>>>(xn, WT_cat, b_cat, nullptr, nullptr,
                                                nullptr, dt16, lnzb, ygb, 12, 3072, D);

  scan_pass1<<<1024, tb, 0, stream>>>(dt16, lnzb, Pc, Sc);
  scan_pass2<<<16, tb, 0, stream>>>(Pc, Sc, hidden, hin);
  scan_pass3<<<1024, tb, 0, stream>>>(dt16, lnzb, hin, h_out, hbf);

  // x1 = (h@w_y + b_y) * silu(yg) + x
  gemm256<2><<<dim3(4 * 64), 512, 0, stream>>>(hbf, WT_y, b_y, ygb, x,
                                               x_out, nullptr, nullptr, nullptr, 4, D, D);

  rmsnorm_kernel<<<M, tb, 0, stream>>>(x_out, g_ffn, xn);

  // gs = silu(xn@w_ffg + b_ffg)
  gemm256<6><<<dim3(16 * 64), 512, 0, stream>>>(xn, WT_ffg, b_ffg, nullptr, nullptr,
                                                nullptr, gs, nullptr, nullptr, 16, F, D);
  // gs = (xn@w_ff + b_ff) * gs   (in-place gated mul)
  gemm256<7><<<dim3(16 * 64), 512, 0, stream>>>(xn, WT_ff, b_ff, gs, nullptr,
                                                nullptr, gs, nullptr, nullptr, 16, F, D);
  // x_out += gs@w_ffo + b_ffo
  gemm256<4><<<dim3(4 * 64), 512, 0, stream>>>(gs, WT_ffo, b_ffo, nullptr, nullptr,
                                               x_out, nullptr, nullptr, nullptr, 4, D, F);
}

// Round 6
// 759.606 us; speedup vs baseline: 1.4509x; 1.0262x over previous
//
#include <hip/hip_runtime.h>
#include <cstdint>
#include <cstddef>

using u16 = unsigned short;
using bf16x8 = __attribute__((ext_vector_type(8))) short;
using f32x4  = __attribute__((ext_vector_type(4))) float;

__device__ __forceinline__ u16 f2bf(float f) {
  unsigned u = __float_as_uint(f);
  u += 0x7fffu + ((u >> 16) & 1u);
  return (u16)(u >> 16);
}
__device__ __forceinline__ float bf2f(u16 h) {
  return __uint_as_float(((unsigned)h) << 16);
}

__device__ __forceinline__ void gload_lds16(const void* g, void* l) {
  auto gp = reinterpret_cast<const __attribute__((address_space(1))) char*>(
      reinterpret_cast<uintptr_t>(g));
  auto lp = reinterpret_cast<__attribute__((address_space(3))) char*>(
      reinterpret_cast<uintptr_t>(l));
  __builtin_amdgcn_global_load_lds(gp, lp, 16, 0, 0);
}

// ---------- weight transpose + downcast: W f32[din][dout] -> WT bf16[dout][din]
__global__ __launch_bounds__(256) void transpose_to_bf16(
    const float* __restrict__ W, u16* __restrict__ WT, int din, int dout) {
  __shared__ float tile[32][33];
  const int j0 = blockIdx.x * 32;   // dout
  const int i0 = blockIdx.y * 32;   // din
  const int tx = threadIdx.x & 31;
  const int ty = threadIdx.x >> 5;  // 0..7
#pragma unroll
  for (int k = 0; k < 32; k += 8)
    tile[ty + k][tx] = W[(size_t)(i0 + ty + k) * dout + (j0 + tx)];
  __syncthreads();
#pragma unroll
  for (int k = 0; k < 32; k += 8)
    WT[(size_t)(j0 + ty + k) * din + (i0 + tx)] = f2bf(tile[tx][ty + k]);
}

// ---------- rmsnorm f32 -> bf16, one block per row of 1024
__global__ __launch_bounds__(256) void rmsnorm_kernel(
    const float* __restrict__ x, const float* __restrict__ g, u16* __restrict__ xn) {
  const int row = blockIdx.x;
  const float4 v = ((const float4*)(x + (size_t)row * 1024))[threadIdx.x];
  float ss = v.x * v.x + v.y * v.y + v.z * v.z + v.w * v.w;
#pragma unroll
  for (int off = 32; off > 0; off >>= 1) ss += __shfl_down(ss, off, 64);
  __shared__ float red[4];
  if ((threadIdx.x & 63) == 0) red[threadIdx.x >> 6] = ss;
  __syncthreads();
  const float rs = rsqrtf((red[0] + red[1] + red[2] + red[3]) * (1.f / 1024.f) + 1e-6f);
  const float4 gv = ((const float4*)g)[threadIdx.x];
  ushort4 o;
  o.x = f2bf(v.x * rs * gv.x);
  o.y = f2bf(v.y * rs * gv.y);
  o.z = f2bf(v.z * rs * gv.z);
  o.w = f2bf(v.w * rs * gv.w);
  ((ushort4*)(xn + (size_t)row * 1024))[threadIdx.x] = o;
}

// ---------- chunked linear-recurrence scan: h[l] = sig(-dt)*h[l-1] + sig(dt)*sig(lnz)
__global__ __launch_bounds__(256) void scan_pass1(
    const u16* __restrict__ dt, const u16* __restrict__ lnz,
    float* __restrict__ P, float* __restrict__ S) {
  const int blk = blockIdx.x;              // B*64*4 = 1024 blocks
  const int dblk = blk & 3;
  const int chunk = (blk >> 2) & 63;
  const int b = blk >> 8;
  const int d = dblk * 256 + threadIdx.x;
  const size_t base = ((size_t)b * 4096 + (size_t)chunk * 64) * 1024 + d;
  float p = 1.f, s = 0.f;
#pragma unroll 8
  for (int l = 0; l < 64; ++l) {
    const float dtv = bf2f(dt[base + (size_t)l * 1024]);
    const float zv = bf2f(lnz[base + (size_t)l * 1024]);
    const float a = 1.f / (1.f + __expf(dtv));        // sigmoid(-dt)
    const float zs = 1.f / (1.f + __expf(-zv));       // sigmoid(lnz_pre)
    const float in = (1.f - a) * zs;
    p *= a;
    s = a * s + in;
  }
  const size_t o = ((size_t)b * 64 + chunk) * 1024 + d;
  P[o] = p;
  S[o] = s;
}

__global__ __launch_bounds__(256) void scan_pass2(
    const float* __restrict__ P, const float* __restrict__ S,
    const float* __restrict__ hidden, float* __restrict__ hin) {
  const int idx = blockIdx.x * 256 + threadIdx.x;  // 0..4095
  const int b = idx >> 10, d = idx & 1023;
  float h = hidden[idx];
#pragma unroll 8
  for (int c = 0; c < 64; ++c) {
    const size_t o = ((size_t)b * 64 + c) * 1024 + d;
    hin[o] = h;
    h = P[o] * h + S[o];
  }
}

__global__ __launch_bounds__(256) void scan_pass3(
    const u16* __restrict__ dt, const u16* __restrict__ lnz,
    const float* __restrict__ hin, float* __restrict__ h_out, u16* __restrict__ hbf) {
  const int blk = blockIdx.x;
  const int dblk = blk & 3;
  const int chunk = (blk >> 2) & 63;
  const int b = blk >> 8;
  const int d = dblk * 256 + threadIdx.x;
  const size_t base = ((size_t)b * 4096 + (size_t)chunk * 64) * 1024 + d;
  float h = hin[((size_t)b * 64 + chunk) * 1024 + d];
#pragma unroll 4
  for (int l = 0; l < 64; ++l) {
    const float dtv = bf2f(dt[base + (size_t)l * 1024]);
    const float zv = bf2f(lnz[base + (size_t)l * 1024]);
    const float a = 1.f / (1.f + __expf(dtv));
    const float zs = 1.f / (1.f + __expf(-zv));
    h = a * h + (1.f - a) * zs;
    h_out[base + (size_t)l * 1024] = h;
    hbf[base + (size_t)l * 1024] = f2bf(h);
  }
}

// ---------- 256x256 GEMM, relaxed-barrier schedule: C = A[M][K] @ B^T (bf16).
// 8 waves (2Mx4N), per-wave 128x64 out, BK=64, ring of 10 half-tile LDS slots
// (160 KiB), lead = 3 half-tiles, counted vmcnt(6), 2 barriers per K-tile:
//  - mid barrier after MMAQ(1,0): every wave's phase-0/2 reads of slot (4t)%10
//    have completed (lgkm dependency of its own MFMAs) before STAGE(pB0)
//    overwrites that slot (half 4t+10).
//  - end barrier after vmcnt(6): halves through 4t+7 retired -> tile t+1
//    fully resident; also bounds wave skew to < 1 tile for all other slots.
// Between barriers, ds_read / global_load_lds / MFMA flow freely so the
// compiler software-pipelines reads under MFMA (counted lgkmcnt).
// EPI: 5 = fused3: bf16 outs {outH=dt, outH2=lnz, outH3=yg}, row stride 1024
//      2 = f32 out = (acc+b)*silu(gate bf16) + resid
//      6 = bf16 out = silu(acc+b)
//      7 = bf16 out = (acc+b)*bf2f(gate)   (gate may alias outH: in-place)
//      4 = f32 out = acc + b + outF (in-place residual add)
template <int EPI>
__global__ __launch_bounds__(512) void gemm256(
    const u16* __restrict__ A, const u16* __restrict__ B,
    const float* __restrict__ bias, const u16* __restrict__ gate,
    const float* __restrict__ resid, float* __restrict__ outF,
    u16* __restrict__ outH, u16* __restrict__ outH2, u16* __restrict__ outH3,
    int ntx, int N, int K) {
  constexpr int SLOT = 16384;
  constexpr int LDSZ = 10 * SLOT;
  const int tid = threadIdx.x;
  const int lane = tid & 63;
  const int wid = tid >> 6;
  const int wr = wid >> 2;   // 0..1 -> A half
  const int wc = wid & 3;    // 0..3 -> 64-col strip; wc>>1 -> B half

  // XCD-aware swizzle (grid %8==0 for all our launches)
  const int nwg = gridDim.x;
  int id = blockIdx.x;
  id = (id & 7) * (nwg >> 3) + (id >> 3);
  const int m0 = (id / ntx) * 256;
  const int n0 = (id % ntx) * 256;

  __shared__ __align__(16) char lds[LDSZ];

  f32x4 acc[8][4];
#pragma unroll
  for (int m = 0; m < 8; ++m)
#pragma unroll
    for (int n = 0; n < 4; ++n) acc[m][n] = (f32x4){0.f, 0.f, 0.f, 0.f};

  bf16x8 aR[4][2], bR[4][2];

  // ---- hoisted LDS read offsets (relative to slot base) ----
  int aOff[4][2], bOff[2][2];
  {
    const int lq = (lane >> 4) << 4;
#pragma unroll
    for (int m = 0; m < 4; ++m) {
      const int hr = m * 16 + (lane & 15);
#pragma unroll
      for (int k = 0; k < 2; ++k)
        aOff[m][k] = hr * 128 + ((k * 64 + lq) ^ ((hr & 7) << 4));
    }
#pragma unroll
    for (int n = 0; n < 2; ++n) {
      const int hr = (wc & 1) * 64 + n * 16 + (lane & 15);
#pragma unroll
      for (int k = 0; k < 2; ++k)
        bOff[n][k] = hr * 128 + ((k * 64 + lq) ^ ((hr & 7) << 4));
    }
  }

  // ---- hoisted stage addressing ----
  const int row0 = tid >> 3;                               // 0..63
  const int kb0  = ((tid & 7) * 16) ^ ((row0 & 7) << 4);   // inverse-swizzled src byte
  const size_t dRow = (size_t)128 * K;                     // +64 rows (bytes)
  const char* pA0 = (const char*)A + (size_t)(m0 + row0) * K * 2 + kb0;
  const char* pA1 = pA0 + (size_t)256 * K;                 // +128 rows
  const char* pB0 = (const char*)B + (size_t)(n0 + row0) * K * 2 + kb0;
  const char* pB1 = pB0 + (size_t)256 * K;
  const int ldst = tid * 16;                               // LDS offset within slot

#define STAGE(PTR, SB)                                                        \
  {                                                                           \
    gload_lds16(PTR, lds + (SB) + ldst);                                      \
    gload_lds16(PTR + dRow, lds + (SB) + ldst + 8192);                        \
    PTR += 128;                                                               \
  }

#define READA(SAB, QM)                                                        \
  _Pragma("unroll") for (int m = 0; m < 4; ++m)                               \
  _Pragma("unroll") for (int k = 0; k < 2; ++k)                               \
    aR[m][k] = *(const bf16x8*)(lds + (SAB) + aOff[m][k] + (QM) * 8192);

#define READB(SBB, NP)                                                        \
  _Pragma("unroll") for (int n = 0; n < 2; ++n)                               \
  _Pragma("unroll") for (int k = 0; k < 2; ++k)                               \
    bR[(NP) + n][k] = *(const bf16x8*)(lds + (SBB) + bOff[n][k] + (NP) * 2048);

#define MMAQ(QM, QN)                                                          \
  __builtin_amdgcn_s_setprio(1);                                              \
  _Pragma("unroll") for (int m = 0; m < 4; ++m)                               \
  _Pragma("unroll") for (int n = 0; n < 2; ++n)                               \
  _Pragma("unroll") for (int k = 0; k < 2; ++k)                               \
      acc[(QM) * 4 + m][(QN) * 2 + n] = __builtin_amdgcn_mfma_f32_16x16x32_bf16( \
          aR[m][k], bR[(QN) * 2 + n][k], acc[(QM) * 4 + m][(QN) * 2 + n], 0, 0, 0); \
  __builtin_amdgcn_s_setprio(0);

  const int NT = K >> 6;

  // prologue: halves 0..6 -> slots 0..6 (tile0 complete + tile1 A0,A1,B0)
  STAGE(pA0, 0 * SLOT);
  STAGE(pA1, 1 * SLOT);
  STAGE(pB0, 2 * SLOT);
  STAGE(pB1, 3 * SLOT);
  STAGE(pA0, 4 * SLOT);
  STAGE(pA1, 5 * SLOT);
  STAGE(pB0, 6 * SLOT);
  asm volatile("s_waitcnt vmcnt(6)" ::: "memory");   // tile0 resident, 3 halves in flight
  __builtin_amdgcn_s_barrier();

  int iA = wr;             // slot of this wave's A half, advances +4 mod 10
  int iB = 2 + (wc >> 1);  // slot of this wave's B half
  int iS = 7;              // stage slot for phase 0

  for (int t = 0; t < NT; ++t) {
    const int sAb = __builtin_amdgcn_readfirstlane(iA * SLOT);
    const int sBb = __builtin_amdgcn_readfirstlane(iB * SLOT);
    int s0 = iS * SLOT;
    int s1 = s0 + SLOT; if (s1 >= LDSZ) s1 -= LDSZ;
    int s2 = s1 + SLOT; if (s2 >= LDSZ) s2 -= LDSZ;
    int s3 = s2 + SLOT; if (s3 >= LDSZ) s3 -= LDSZ;
    const bool st0 = (t <= NT - 2);     // stage B1 of tile t+1
    const bool st123 = (t <= NT - 3);   // stage A0/A1/B0 of tile t+2
    // free-flowing span: reads + stages + 48 MFMA, no barriers
    READA(sAb, 0);
    READB(sBb, 0);
    if (st0) STAGE(pB1, s0);
    MMAQ(0, 0);
    READB(sBb, 2);
    if (st123) STAGE(pA0, s1);
    MMAQ(0, 1);
    READA(sAb, 1);
    if (st123) STAGE(pA1, s2);
    MMAQ(1, 0);
    // mid barrier: all waves' reads of slot (4t)%10 are complete (consumed by
    // MMAQ(0,0)/MMAQ(1,0) lgkm waits) before it is overwritten below.
    __builtin_amdgcn_s_barrier();
    if (st123) STAGE(pB0, s3);
    MMAQ(1, 1);
    if (t < NT - 2) asm volatile("s_waitcnt vmcnt(6)" ::: "memory");
    else            asm volatile("s_waitcnt vmcnt(0)" ::: "memory");
    __builtin_amdgcn_s_barrier();
    iA += 4; if (iA >= 10) iA -= 10;
    iB += 4; if (iB >= 10) iB -= 10;
    iS += 4; if (iS >= 10) iS -= 10;
  }

  // epilogue: C/D layout col = lane&15, row = (lane>>4)*4 + j
#pragma unroll
  for (int m = 0; m < 8; ++m) {
#pragma unroll
    for (int n = 0; n < 4; ++n) {
      const int col = n0 + wc * 64 + n * 16 + (lane & 15);
#pragma unroll
      for (int j = 0; j < 4; ++j) {
        const int row = m0 + wr * 128 + m * 16 + ((lane >> 4) << 2) + j;
        const float v = acc[m][n][j] + bias[col];
        if constexpr (EPI == 5) {
          const int rg = col >> 10;                     // block-uniform
          const size_t o = (size_t)row * 1024 + (col & 1023);
          if (rg == 0) outH[o] = f2bf(v);
          else if (rg == 1) outH2[o] = f2bf(v);
          else outH3[o] = f2bf(v);
        } else {
          const size_t o = (size_t)row * N + col;
          if constexpr (EPI == 2) {
            const float gt = bf2f(gate[o]);
            outF[o] = v * (gt / (1.f + __expf(-gt))) + resid[o];
          } else if constexpr (EPI == 6) {
            outH[o] = f2bf(v / (1.f + __expf(-v)));
          } else if constexpr (EPI == 7) {
            outH[o] = f2bf(v * bf2f(gate[o]));          // gate==outH ok (RAW per elem)
          } else if constexpr (EPI == 4) {
            outF[o] = v + outF[o];
          }
        }
      }
    }
  }
#undef STAGE
#undef READA
#undef READB
#undef MMAQ
}

extern "C" void kernel_launch(void* const* d_in, const int* in_sizes, int n_in,
                              void* d_out, int out_size, void* d_ws, size_t ws_size,
                              hipStream_t stream) {
  const float* x      = (const float*)d_in[0];
  const float* hidden = (const float*)d_in[1];
  const float* w_ln_z = (const float*)d_in[2];
  const float* b_ln_z = (const float*)d_in[3];
  const float* w_dt   = (const float*)d_in[4];
  const float* b_dt   = (const float*)d_in[5];
  const float* w_y    = (const float*)d_in[6];
  const float* b_y    = (const float*)d_in[7];
  const float* w_yg   = (const float*)d_in[8];
  const float* b_yg   = (const float*)d_in[9];
  const float* w_ff   = (const float*)d_in[10];
  const float* b_ff   = (const float*)d_in[11];
  const float* w_ffg  = (const float*)d_in[12];
  const float* b_ffg  = (const float*)d_in[13];
  const float* w_ffo  = (const float*)d_in[14];
  const float* b_ffo  = (const float*)d_in[15];
  const float* g_sio  = (const float*)d_in[16];
  const float* g_ffn  = (const float*)d_in[17];

  char* ws = (char*)d_ws;
  const size_t MB = 1ull << 20;
  u16*   WT_cat = (u16*)(ws + 0 * MB);      // 6 MiB  [3072][1024] (dt|lnz|yg)
  u16*   WT_y   = (u16*)(ws + 8 * MB);      // 2 MiB
  u16*   WT_ff  = (u16*)(ws + 10 * MB);     // 8 MiB  [4096][1024]
  u16*   WT_ffg = (u16*)(ws + 18 * MB);     // 8 MiB
  u16*   WT_ffo = (u16*)(ws + 26 * MB);     // 8 MiB  [1024][4096]
  float* b_cat  = (float*)(ws + 34 * MB);   // 12 KiB [3072]
  u16*   xn     = (u16*)(ws + 36 * MB);     // 32 MiB [16384][1024] bf16
  u16*   dt16   = (u16*)(ws + 68 * MB);     // 32 MiB bf16
  u16*   lnzb   = (u16*)(ws + 100 * MB);    // 32 MiB
  u16*   ygb    = (u16*)(ws + 132 * MB);    // 32 MiB
  u16*   hbf    = (u16*)(ws + 164 * MB);    // 32 MiB
  float* Pc     = (float*)(ws + 196 * MB);  // 1 MiB
  float* Sc     = (float*)(ws + 197 * MB);  // 1 MiB
  float* hin    = (float*)(ws + 198 * MB);  // 1 MiB
  u16*   gs     = (u16*)(ws + 68 * MB);     // 128 MiB overlay [16384][4096]
  // peak ws usage: 199 MiB

  float* x_out = (float*)d_out;
  float* h_out = (float*)d_out + (size_t)4 * 4096 * 1024;

  const int M = 16384, D = 1024, F = 4096;
  const dim3 tb(256);

  transpose_to_bf16<<<dim3(32, 32), tb, 0, stream>>>(w_dt, WT_cat, D, D);
  transpose_to_bf16<<<dim3(32, 32), tb, 0, stream>>>(w_ln_z, WT_cat + 1024 * 1024, D, D);
  transpose_to_bf16<<<dim3(32, 32), tb, 0, stream>>>(w_yg, WT_cat + 2 * 1024 * 1024, D, D);
  transpose_to_bf16<<<dim3(32, 32), tb, 0, stream>>>(w_y, WT_y, D, D);
  transpose_to_bf16<<<dim3(128, 32), tb, 0, stream>>>(w_ff, WT_ff, D, F);
  transpose_to_bf16<<<dim3(128, 32), tb, 0, stream>>>(w_ffg, WT_ffg, D, F);
  transpose_to_bf16<<<dim3(32, 128), tb, 0, stream>>>(w_ffo, WT_ffo, F, D);
  (void)hipMemcpyAsync(b_cat, b_dt, D * 4, hipMemcpyDeviceToDevice, stream);
  (void)hipMemcpyAsync(b_cat + 1024, b_ln_z, D * 4, hipMemcpyDeviceToDevice, stream);
  (void)hipMemcpyAsync(b_cat + 2048, b_yg, D * 4, hipMemcpyDeviceToDevice, stream);

  rmsnorm_kernel<<<M, tb, 0, stream>>>(x, g_sio, xn);

  // fused dt|lnz|yg GEMM: N=3072
  gemm256<5><<<dim3(12 * 64), 512, 0, stream>>>(xn, WT_cat, b_cat, nullptr, nullptr,
                                                nullptr, dt16, lnzb, ygb, 12, 3072, D);

  scan_pass1<<<1024, tb, 0, stream>>>(dt16, lnzb, Pc, Sc);
  scan_pass2<<<16, tb, 0, stream>>>(Pc, Sc, hidden, hin);
  scan_pass3<<<1024, tb, 0, stream>>>(dt16, lnzb, hin, h_out, hbf);

  // x1 = (h@w_y + b_y) * silu(yg) + x
  gemm256<2><<<dim3(4 * 64), 512, 0, stream>>>(hbf, WT_y, b_y, ygb, x,
                                               x_out, nullptr, nullptr, nullptr, 4, D, D);

  rmsnorm_kernel<<<M, tb, 0, stream>>>(x_out, g_ffn, xn);

  // gs = silu(xn@w_ffg + b_ffg)
  gemm256<6><<<dim3(16 * 64), 512, 0, stream>>>(xn, WT_ffg, b_ffg, nullptr, nullptr,
                                                nullptr, gs, nullptr, nullptr, 16, F, D);
  // gs = (xn@w_ff + b_ff) * gs   (in-place gated mul)
  gemm256<7><<<dim3(16 * 64), 512, 0, stream>>>(xn, WT_ff, b_ff, gs, nullptr,
                                                nullptr, gs, nullptr, nullptr, 16, F, D);
  // x_out += gs@w_ffo + b_ffo
  gemm256<4><<<dim3(4 * 64), 512, 0, stream>>>(gs, WT_ffo, b_ffo, nullptr, nullptr,
                                               x_out, nullptr, nullptr, nullptr, 4, D, F);
}